// Round 2
// baseline (15357.152 us; speedup 1.0000x reference)
//
#include <hip/hip_runtime.h>
#include <hip/hip_bf16.h>
#include <math.h>

#define B_ 2
#define S_ 1024
#define V_ 32000
#define D_ 768
#define F_ 3072
#define H_ 12
#define L_ 6
#define DH_ 64
#define BS_ (B_*S_)   // 2048

// ---------------- embedding ----------------
__global__ void embed_k(const int* __restrict__ x, const float* __restrict__ tok,
                        const float* __restrict__ pos, float* __restrict__ h) {
    int bs = blockIdx.x;           // 0..BS_-1
    int s = bs % S_;
    int t = x[bs];
    for (int d = threadIdx.x; d < D_; d += blockDim.x)
        h[(size_t)bs * D_ + d] = tok[(size_t)t * D_ + d] + pos[(size_t)s * D_ + d];
}

// ---------------- generic tiled fp32 GEMM: C = act(A[M,K] @ W[K,N] + bias) ----------------
// ACT: 0=none, 1=exact gelu.
template<int ACT>
__global__ __launch_bounds__(256) void gemm_k(const float* __restrict__ A,
                                              const float* __restrict__ W,
                                              const float* __restrict__ bias,
                                              float* __restrict__ Cout,
                                              int M, int N, int K) {
    __shared__ float As[64][16];   // [m][k]
    __shared__ float Bs[16][64];   // [k][n]
    const int tid = threadIdx.x;
    const int tx = tid & 15, ty = tid >> 4;
    const int row0 = blockIdx.y * 64, col0 = blockIdx.x * 64;
    float acc[4][4] = {};

    for (int kk = 0; kk < K; kk += 16) {
        #pragma unroll
        for (int it = 0; it < 4; ++it) {
            int idx = tid + it * 256;          // 0..1023
            int m = idx >> 4, k = idx & 15;    // A tile load
            As[m][k] = A[(size_t)(row0 + m) * K + kk + k];
            int r = idx >> 6, c = idx & 63;    // W tile load
            Bs[r][c] = W[(size_t)(kk + r) * N + col0 + c];
        }
        __syncthreads();
        #pragma unroll
        for (int k = 0; k < 16; ++k) {
            float a[4], b[4];
            #pragma unroll
            for (int i = 0; i < 4; ++i) a[i] = As[ty * 4 + i][k];
            #pragma unroll
            for (int j = 0; j < 4; ++j) b[j] = Bs[k][tx * 4 + j];
            #pragma unroll
            for (int i = 0; i < 4; ++i)
                #pragma unroll
                for (int j = 0; j < 4; ++j)
                    acc[i][j] += a[i] * b[j];
        }
        __syncthreads();
    }

    #pragma unroll
    for (int i = 0; i < 4; ++i) {
        int r = row0 + ty * 4 + i;
        #pragma unroll
        for (int j = 0; j < 4; ++j) {
            int c = col0 + tx * 4 + j;
            float v = acc[i][j] + bias[c];
            if (ACT == 1) v = 0.5f * v * (1.0f + erff(v * 0.70710678118654752f));
            Cout[(size_t)r * N + c] = v;
        }
    }
}

// ---------------- attention: one block per (b, h, q_row) ----------------
__global__ __launch_bounds__(256) void attn_k(const float* __restrict__ q,
                                              const float* __restrict__ k,
                                              const float* __restrict__ v,
                                              float* __restrict__ o) {
    const int bid = blockIdx.x;            // 0 .. B*H*S-1
    const int qrow = bid & (S_ - 1);
    const int bh = bid >> 10;              // 0..23
    const int b = bh / H_, hh = bh % H_;
    __shared__ float qs[DH_];
    __shared__ float sc[S_];
    __shared__ float red[256];
    const int tid = threadIdx.x;
    const size_t base = ((size_t)b * S_) * D_ + (size_t)hh * DH_;

    if (tid < DH_) qs[tid] = q[base + (size_t)qrow * D_ + tid] * 0.03608439182435161f; // 1/sqrt(768)
    __syncthreads();

    // scores
    for (int ss = tid; ss < S_; ss += 256) {
        const float* kp = k + base + (size_t)ss * D_;
        float acc = 0.f;
        #pragma unroll
        for (int d = 0; d < DH_; ++d) acc += qs[d] * kp[d];
        sc[ss] = acc;
    }
    __syncthreads();

    // max
    float m = -1e30f;
    for (int ss = tid; ss < S_; ss += 256) m = fmaxf(m, sc[ss]);
    red[tid] = m; __syncthreads();
    for (int st = 128; st > 0; st >>= 1) { if (tid < st) red[tid] = fmaxf(red[tid], red[tid + st]); __syncthreads(); }
    m = red[0]; __syncthreads();

    // exp + sum
    float l = 0.f;
    for (int ss = tid; ss < S_; ss += 256) { float p = __expf(sc[ss] - m); sc[ss] = p; l += p; }
    red[tid] = l; __syncthreads();
    for (int st = 128; st > 0; st >>= 1) { if (tid < st) red[tid] += red[tid + st]; __syncthreads(); }
    float inv = 1.0f / red[0];
    __syncthreads();

    // PV: thread t -> d = t&63, s-chunk = t>>6
    const int d = tid & 63, chunk = tid >> 6;
    float acc = 0.f;
    const float* vp = v + base + d;
    for (int ss = chunk * 256; ss < chunk * 256 + 256; ++ss)
        acc += sc[ss] * vp[(size_t)ss * D_];
    red[tid] = acc; __syncthreads();
    if (tid < 64) {
        float r = red[d] + red[64 + d] + red[128 + d] + red[192 + d];
        o[base + (size_t)qrow * D_ + d] = r * inv;
    }
}

// ---------------- add + layernorm: out = LN(a + b) * g + beta ----------------
__global__ __launch_bounds__(256) void addln_k(const float* __restrict__ a,
                                               const float* __restrict__ b,
                                               const float* __restrict__ g,
                                               const float* __restrict__ beta,
                                               float* __restrict__ out) {
    const int r = blockIdx.x;
    const int tid = threadIdx.x;
    __shared__ float red[256];
    float xv[3];
    float s = 0.f;
    #pragma unroll
    for (int i = 0; i < 3; ++i) {
        int d = tid + i * 256;
        xv[i] = a[(size_t)r * D_ + d] + b[(size_t)r * D_ + d];
        s += xv[i];
    }
    red[tid] = s; __syncthreads();
    for (int st = 128; st > 0; st >>= 1) { if (tid < st) red[tid] += red[tid + st]; __syncthreads(); }
    float mu = red[0] * (1.0f / D_);
    __syncthreads();
    s = 0.f;
    #pragma unroll
    for (int i = 0; i < 3; ++i) { float dd = xv[i] - mu; s += dd * dd; }
    red[tid] = s; __syncthreads();
    for (int st = 128; st > 0; st >>= 1) { if (tid < st) red[tid] += red[tid + st]; __syncthreads(); }
    float rstd = rsqrtf(red[0] * (1.0f / D_) + 1e-5f);
    #pragma unroll
    for (int i = 0; i < 3; ++i) {
        int d = tid + i * 256;
        out[(size_t)r * D_ + d] = (xv[i] - mu) * rstd * g[d] + beta[d];
    }
}

// ---------------- in-place log-softmax over f32 logits rows ----------------
__global__ __launch_bounds__(256) void lsm_k(float* __restrict__ lp) {
    const int r = blockIdx.x;              // 0..BS_-1
    const int tid = threadIdx.x;
    __shared__ float red[256];
    float* row = lp + (size_t)r * V_;
    float m = -1e30f;
    for (int c = tid; c < V_; c += 256) m = fmaxf(m, row[c]);
    red[tid] = m; __syncthreads();
    for (int st = 128; st > 0; st >>= 1) { if (tid < st) red[tid] = fmaxf(red[tid], red[tid + st]); __syncthreads(); }
    m = red[0]; __syncthreads();
    float l = 0.f;
    for (int c = tid; c < V_; c += 256) l += __expf(row[c] - m);
    red[tid] = l; __syncthreads();
    for (int st = 128; st > 0; st >>= 1) { if (tid < st) red[tid] += red[tid + st]; __syncthreads(); }
    float sub = m + __logf(red[0]);
    for (int c = tid; c < V_; c += 256) row[c] = row[c] - sub;
}

extern "C" void kernel_launch(void* const* d_in, const int* in_sizes, int n_in,
                              void* d_out, int out_size, void* d_ws, size_t ws_size,
                              hipStream_t stream) {
    const int*   x    = (const int*)  d_in[0];
    const float* tok  = (const float*)d_in[1];
    const float* pos  = (const float*)d_in[2];
    const float* Wq   = (const float*)d_in[3];
    const float* bq   = (const float*)d_in[4];
    const float* Wk   = (const float*)d_in[5];
    const float* bk   = (const float*)d_in[6];
    const float* Wv   = (const float*)d_in[7];
    const float* bv   = (const float*)d_in[8];
    const float* Wo   = (const float*)d_in[9];
    const float* bo   = (const float*)d_in[10];
    const float* ln1g = (const float*)d_in[11];
    const float* ln1b = (const float*)d_in[12];
    const float* W1   = (const float*)d_in[13];
    const float* b1   = (const float*)d_in[14];
    const float* W2   = (const float*)d_in[15];
    const float* b2   = (const float*)d_in[16];
    const float* ln2g = (const float*)d_in[17];
    const float* ln2b = (const float*)d_in[18];
    const float* Wf   = (const float*)d_in[19];
    const float* bff  = (const float*)d_in[20];

    // d_out: 67,108,864 f32. Layout:
    //   [0, BS*V)        = logits/log_probs (final)  -- used as scratch during layers
    //   [BS*V, end)      = hset (final) = exactly BS*D floats -- `h` lives here the whole time
    float* out = (float*)d_out;
    const size_t HS = (size_t)BS_ * D_;          // 1,572,864
    float* h   = out + (size_t)BS_ * V_;         // tail: IS output 1 when done
    float* q   = out + 0 * HS;                   // scratch inside logits region
    float* k   = out + 1 * HS;
    float* v   = out + 2 * HS;
    float* att = out + 3 * HS;
    float* tmp = out + 4 * HS;
    float* h1  = out + 5 * HS;
    float* ff  = out + 6 * HS;                   // BS*F floats, ends ~15.7M << 65.5M

    embed_k<<<BS_, 256, 0, stream>>>(x, tok, pos, h);

    const dim3 gD(D_ / 64, BS_ / 64);            // (12, 32)
    const dim3 gF(F_ / 64, BS_ / 64);            // (48, 32)
    for (int i = 0; i < L_; ++i) {
        const float* wq = Wq + (size_t)i * D_ * D_;
        const float* wk = Wk + (size_t)i * D_ * D_;
        const float* wv = Wv + (size_t)i * D_ * D_;
        const float* wo = Wo + (size_t)i * D_ * D_;
        const float* w1 = W1 + (size_t)i * D_ * F_;
        const float* w2 = W2 + (size_t)i * F_ * D_;

        gemm_k<0><<<gD, 256, 0, stream>>>(h, wq, bq + (size_t)i * D_, q, BS_, D_, D_);
        gemm_k<0><<<gD, 256, 0, stream>>>(h, wk, bk + (size_t)i * D_, k, BS_, D_, D_);
        gemm_k<0><<<gD, 256, 0, stream>>>(h, wv, bv + (size_t)i * D_, v, BS_, D_, D_);
        attn_k<<<B_ * H_ * S_, 256, 0, stream>>>(q, k, v, att);
        gemm_k<0><<<gD, 256, 0, stream>>>(att, wo, bo + (size_t)i * D_, tmp, BS_, D_, D_);
        addln_k<<<BS_, 256, 0, stream>>>(tmp, h, ln1g + (size_t)i * D_, ln1b + (size_t)i * D_, h1);
        gemm_k<1><<<gF, 256, 0, stream>>>(h1, w1, b1 + (size_t)i * F_, ff, BS_, F_, D_);
        gemm_k<0><<<gD, 256, 0, stream>>>(ff, w2, b2 + (size_t)i * D_, tmp, BS_, D_, F_);
        addln_k<<<BS_, 256, 0, stream>>>(tmp, h1, ln2g + (size_t)i * D_, ln2b + (size_t)i * D_, h);
    }

    // logits = h @ Wf + bf  -> overwrites the scratch region; h (tail) survives as hset output
    gemm_k<0><<<dim3(V_ / 64, BS_ / 64), 256, 0, stream>>>(h, Wf, bff, out, BS_, V_, D_);
    lsm_k<<<BS_, 256, 0, stream>>>(out);
}

// Round 3
// 6498.093 us; speedup vs baseline: 2.3633x; 2.3633x over previous
//
#include <hip/hip_runtime.h>
#include <hip/hip_bf16.h>
#include <math.h>

#define B_ 2
#define S_ 1024
#define V_ 32000
#define D_ 768
#define F_ 3072
#define H_ 12
#define L_ 6
#define DH_ 64
#define BS_ (B_*S_)   // 2048

#define QT_ 32
#define KT_ 64
#define PAD_ 65

// ---------------- embedding ----------------
__global__ void embed_k(const int* __restrict__ x, const float* __restrict__ tok,
                        const float* __restrict__ pos, float* __restrict__ h) {
    int bs = blockIdx.x;           // 0..BS_-1
    int s = bs % S_;
    int t = x[bs];
    for (int d = threadIdx.x; d < D_; d += blockDim.x)
        h[(size_t)bs * D_ + d] = tok[(size_t)t * D_ + d] + pos[(size_t)s * D_ + d];
}

// ---------------- generic tiled fp32 GEMM: C = act(A[M,K] @ W[K,N] + bias) ----------------
// ACT: 0=none, 1=exact gelu.
template<int ACT>
__global__ __launch_bounds__(256) void gemm_k(const float* __restrict__ A,
                                              const float* __restrict__ W,
                                              const float* __restrict__ bias,
                                              float* __restrict__ Cout,
                                              int M, int N, int K) {
    __shared__ float As[64][16];   // [m][k]
    __shared__ float Bs[16][64];   // [k][n]
    const int tid = threadIdx.x;
    const int tx = tid & 15, ty = tid >> 4;
    const int row0 = blockIdx.y * 64, col0 = blockIdx.x * 64;
    float acc[4][4] = {};

    for (int kk = 0; kk < K; kk += 16) {
        #pragma unroll
        for (int it = 0; it < 4; ++it) {
            int idx = tid + it * 256;          // 0..1023
            int m = idx >> 4, k = idx & 15;    // A tile load
            As[m][k] = A[(size_t)(row0 + m) * K + kk + k];
            int r = idx >> 6, c = idx & 63;    // W tile load
            Bs[r][c] = W[(size_t)(kk + r) * N + col0 + c];
        }
        __syncthreads();
        #pragma unroll
        for (int k = 0; k < 16; ++k) {
            float a[4], b[4];
            #pragma unroll
            for (int i = 0; i < 4; ++i) a[i] = As[ty * 4 + i][k];
            #pragma unroll
            for (int j = 0; j < 4; ++j) b[j] = Bs[k][tx * 4 + j];
            #pragma unroll
            for (int i = 0; i < 4; ++i)
                #pragma unroll
                for (int j = 0; j < 4; ++j)
                    acc[i][j] += a[i] * b[j];
        }
        __syncthreads();
    }

    #pragma unroll
    for (int i = 0; i < 4; ++i) {
        int r = row0 + ty * 4 + i;
        #pragma unroll
        for (int j = 0; j < 4; ++j) {
            int c = col0 + tx * 4 + j;
            float v = acc[i][j] + bias[c];
            if (ACT == 1) v = 0.5f * v * (1.0f + erff(v * 0.70710678118654752f));
            Cout[(size_t)r * N + c] = v;
        }
    }
}

// ---------------- flash-style attention ----------------
// grid: (S/QT, B*H). Block: 256 threads. Thread (tx=tid&15, ty=tid>>4) owns
// rows {ty*2, ty*2+1} of the Q-tile and cols {tx*4..+3} (k-cols for scores,
// d-cols for PV). Online softmax state (m,l) per row, replicated across the
// 16-lane tx group, reduced via __shfl_xor (masks 1,2,4,8 stay in-group).
__global__ __launch_bounds__(256) void fattn_k(const float* __restrict__ q,
                                               const float* __restrict__ k,
                                               const float* __restrict__ v,
                                               float* __restrict__ o) {
    const int qt0 = blockIdx.x * QT_;
    const int bh = blockIdx.y;
    const int b = bh / H_, hh = bh % H_;
    const size_t base = ((size_t)b * S_) * D_ + (size_t)hh * DH_;

    __shared__ float Qs[QT_][PAD_];
    __shared__ float Ks[KT_][PAD_];
    __shared__ float Vs[KT_][PAD_];
    __shared__ float Ps[QT_][PAD_];

    const int tid = threadIdx.x;
    const int tx = tid & 15;
    const int ty = tid >> 4;
    const int r0 = ty * 2, c0 = tx * 4;

    // load Q tile (pre-scaled)
    for (int i = tid; i < QT_ * DH_; i += 256) {
        int r = i >> 6, d = i & 63;
        Qs[r][d] = q[base + (size_t)(qt0 + r) * D_ + d] * 0.03608439182435161f; // 1/sqrt(768)
    }

    float m_i[2] = {-1e30f, -1e30f};
    float l_i[2] = {0.f, 0.f};
    float oacc[2][4] = {};

    for (int kt0 = 0; kt0 < S_; kt0 += KT_) {
        __syncthreads();                       // Qs ready (iter 0) / Ks,Vs,Ps free
        for (int i = tid; i < KT_ * DH_; i += 256) {
            int r = i >> 6, d = i & 63;
            Ks[r][d] = k[base + (size_t)(kt0 + r) * D_ + d];
            Vs[r][d] = v[base + (size_t)(kt0 + r) * D_ + d];
        }
        __syncthreads();

        // ---- scores s = Q @ K^T (2x4 per thread) ----
        float s[2][4] = {};
        #pragma unroll 8
        for (int d = 0; d < DH_; ++d) {
            float q0v = Qs[r0 + 0][d];
            float q1v = Qs[r0 + 1][d];
            float kv0 = Ks[c0 + 0][d];
            float kv1 = Ks[c0 + 1][d];
            float kv2 = Ks[c0 + 2][d];
            float kv3 = Ks[c0 + 3][d];
            s[0][0] += q0v * kv0; s[0][1] += q0v * kv1; s[0][2] += q0v * kv2; s[0][3] += q0v * kv3;
            s[1][0] += q1v * kv0; s[1][1] += q1v * kv1; s[1][2] += q1v * kv2; s[1][3] += q1v * kv3;
        }

        // ---- online softmax update ----
        #pragma unroll
        for (int i = 0; i < 2; ++i) {
            float tmax = fmaxf(fmaxf(s[i][0], s[i][1]), fmaxf(s[i][2], s[i][3]));
            #pragma unroll
            for (int off = 1; off <= 8; off <<= 1)
                tmax = fmaxf(tmax, __shfl_xor(tmax, off));
            float mnew = fmaxf(m_i[i], tmax);
            float corr = __expf(m_i[i] - mnew);
            m_i[i] = mnew;
            float psum = 0.f;
            #pragma unroll
            for (int j = 0; j < 4; ++j) {
                float p = __expf(s[i][j] - mnew);
                Ps[r0 + i][c0 + j] = p;
                psum += p;
            }
            #pragma unroll
            for (int off = 1; off <= 8; off <<= 1)
                psum += __shfl_xor(psum, off);
            l_i[i] = l_i[i] * corr + psum;
            #pragma unroll
            for (int j = 0; j < 4; ++j) oacc[i][j] *= corr;
        }
        __syncthreads();                        // Ps ready

        // ---- PV: O += P @ V (2x4 per thread, d-cols = c0..c0+3) ----
        #pragma unroll 8
        for (int kk = 0; kk < KT_; ++kk) {
            float p0 = Ps[r0 + 0][kk];
            float p1 = Ps[r0 + 1][kk];
            float v0 = Vs[kk][c0 + 0];
            float v1 = Vs[kk][c0 + 1];
            float v2 = Vs[kk][c0 + 2];
            float v3 = Vs[kk][c0 + 3];
            oacc[0][0] += p0 * v0; oacc[0][1] += p0 * v1; oacc[0][2] += p0 * v2; oacc[0][3] += p0 * v3;
            oacc[1][0] += p1 * v0; oacc[1][1] += p1 * v1; oacc[1][2] += p1 * v2; oacc[1][3] += p1 * v3;
        }
    }

    #pragma unroll
    for (int i = 0; i < 2; ++i) {
        float inv = 1.0f / l_i[i];
        #pragma unroll
        for (int j = 0; j < 4; ++j)
            o[base + (size_t)(qt0 + r0 + i) * D_ + c0 + j] = oacc[i][j] * inv;
    }
}

// ---------------- add + layernorm: out = LN(a + b) * g + beta ----------------
__global__ __launch_bounds__(256) void addln_k(const float* __restrict__ a,
                                               const float* __restrict__ b,
                                               const float* __restrict__ g,
                                               const float* __restrict__ beta,
                                               float* __restrict__ out) {
    const int r = blockIdx.x;
    const int tid = threadIdx.x;
    __shared__ float red[256];
    float xv[3];
    float s = 0.f;
    #pragma unroll
    for (int i = 0; i < 3; ++i) {
        int d = tid + i * 256;
        xv[i] = a[(size_t)r * D_ + d] + b[(size_t)r * D_ + d];
        s += xv[i];
    }
    red[tid] = s; __syncthreads();
    for (int st = 128; st > 0; st >>= 1) { if (tid < st) red[tid] += red[tid + st]; __syncthreads(); }
    float mu = red[0] * (1.0f / D_);
    __syncthreads();
    s = 0.f;
    #pragma unroll
    for (int i = 0; i < 3; ++i) { float dd = xv[i] - mu; s += dd * dd; }
    red[tid] = s; __syncthreads();
    for (int st = 128; st > 0; st >>= 1) { if (tid < st) red[tid] += red[tid + st]; __syncthreads(); }
    float rstd = rsqrtf(red[0] * (1.0f / D_) + 1e-5f);
    #pragma unroll
    for (int i = 0; i < 3; ++i) {
        int d = tid + i * 256;
        out[(size_t)r * D_ + d] = (xv[i] - mu) * rstd * g[d] + beta[d];
    }
}

// ---------------- in-place log-softmax over f32 logits rows ----------------
__global__ __launch_bounds__(256) void lsm_k(float* __restrict__ lp) {
    const int r = blockIdx.x;              // 0..BS_-1
    const int tid = threadIdx.x;
    __shared__ float red[256];
    float* row = lp + (size_t)r * V_;
    float m = -1e30f;
    for (int c = tid; c < V_; c += 256) m = fmaxf(m, row[c]);
    red[tid] = m; __syncthreads();
    for (int st = 128; st > 0; st >>= 1) { if (tid < st) red[tid] = fmaxf(red[tid], red[tid + st]); __syncthreads(); }
    m = red[0]; __syncthreads();
    float l = 0.f;
    for (int c = tid; c < V_; c += 256) l += __expf(row[c] - m);
    red[tid] = l; __syncthreads();
    for (int st = 128; st > 0; st >>= 1) { if (tid < st) red[tid] += red[tid + st]; __syncthreads(); }
    float sub = m + __logf(red[0]);
    for (int c = tid; c < V_; c += 256) row[c] = row[c] - sub;
}

extern "C" void kernel_launch(void* const* d_in, const int* in_sizes, int n_in,
                              void* d_out, int out_size, void* d_ws, size_t ws_size,
                              hipStream_t stream) {
    const int*   x    = (const int*)  d_in[0];
    const float* tok  = (const float*)d_in[1];
    const float* pos  = (const float*)d_in[2];
    const float* Wq   = (const float*)d_in[3];
    const float* bq   = (const float*)d_in[4];
    const float* Wk   = (const float*)d_in[5];
    const float* bk   = (const float*)d_in[6];
    const float* Wv   = (const float*)d_in[7];
    const float* bv   = (const float*)d_in[8];
    const float* Wo   = (const float*)d_in[9];
    const float* bo   = (const float*)d_in[10];
    const float* ln1g = (const float*)d_in[11];
    const float* ln1b = (const float*)d_in[12];
    const float* W1   = (const float*)d_in[13];
    const float* b1   = (const float*)d_in[14];
    const float* W2   = (const float*)d_in[15];
    const float* b2   = (const float*)d_in[16];
    const float* ln2g = (const float*)d_in[17];
    const float* ln2b = (const float*)d_in[18];
    const float* Wf   = (const float*)d_in[19];
    const float* bff  = (const float*)d_in[20];

    // d_out: 67,108,864 f32. Layout:
    //   [0, BS*V)        = logits/log_probs (final)  -- used as scratch during layers
    //   [BS*V, end)      = hset (final) = exactly BS*D floats -- `h` lives here the whole time
    float* out = (float*)d_out;
    const size_t HS = (size_t)BS_ * D_;          // 1,572,864
    float* h   = out + (size_t)BS_ * V_;         // tail: IS output 1 when done
    float* q   = out + 0 * HS;                   // scratch inside logits region
    float* k   = out + 1 * HS;
    float* v   = out + 2 * HS;
    float* att = out + 3 * HS;
    float* tmp = out + 4 * HS;
    float* h1  = out + 5 * HS;
    float* ff  = out + 6 * HS;                   // BS*F floats, ends ~15.7M << 65.5M

    embed_k<<<BS_, 256, 0, stream>>>(x, tok, pos, h);

    const dim3 gD(D_ / 64, BS_ / 64);            // (12, 32)
    const dim3 gF(F_ / 64, BS_ / 64);            // (48, 32)
    const dim3 gA(S_ / QT_, B_ * H_);            // (32, 24)
    for (int i = 0; i < L_; ++i) {
        const float* wq = Wq + (size_t)i * D_ * D_;
        const float* wk = Wk + (size_t)i * D_ * D_;
        const float* wv = Wv + (size_t)i * D_ * D_;
        const float* wo = Wo + (size_t)i * D_ * D_;
        const float* w1 = W1 + (size_t)i * D_ * F_;
        const float* w2 = W2 + (size_t)i * F_ * D_;

        gemm_k<0><<<gD, 256, 0, stream>>>(h, wq, bq + (size_t)i * D_, q, BS_, D_, D_);
        gemm_k<0><<<gD, 256, 0, stream>>>(h, wk, bk + (size_t)i * D_, k, BS_, D_, D_);
        gemm_k<0><<<gD, 256, 0, stream>>>(h, wv, bv + (size_t)i * D_, v, BS_, D_, D_);
        fattn_k<<<gA, 256, 0, stream>>>(q, k, v, att);
        gemm_k<0><<<gD, 256, 0, stream>>>(att, wo, bo + (size_t)i * D_, tmp, BS_, D_, D_);
        addln_k<<<BS_, 256, 0, stream>>>(tmp, h, ln1g + (size_t)i * D_, ln1b + (size_t)i * D_, h1);
        gemm_k<1><<<gF, 256, 0, stream>>>(h1, w1, b1 + (size_t)i * F_, ff, BS_, F_, D_);
        gemm_k<0><<<gD, 256, 0, stream>>>(ff, w2, b2 + (size_t)i * D_, tmp, BS_, D_, F_);
        addln_k<<<BS_, 256, 0, stream>>>(tmp, h1, ln2g + (size_t)i * D_, ln2b + (size_t)i * D_, h);
    }

    // logits = h @ Wf + bf  -> overwrites the scratch region; h (tail) survives as hset output
    gemm_k<0><<<dim3(V_ / 64, BS_ / 64), 256, 0, stream>>>(h, Wf, bff, out, BS_, V_, D_);
    lsm_k<<<BS_, 256, 0, stream>>>(out);
}

// Round 4
// 2664.409 us; speedup vs baseline: 5.7638x; 2.4388x over previous
//
#include <hip/hip_runtime.h>
#include <hip/hip_bf16.h>
#include <math.h>

#define B_ 2
#define S_ 1024
#define V_ 32000
#define D_ 768
#define F_ 3072
#define H_ 12
#define L_ 6
#define DH_ 64
#define BS_ (B_*S_)   // 2048
#define NQKV_ 2304

#define QT_ 32
#define KT_ 64
#define PAD_ 65

typedef __attribute__((ext_vector_type(8))) short short8;
typedef __attribute__((ext_vector_type(4))) float f32x4;

__device__ __forceinline__ unsigned short f2b(float f) {
    union { __hip_bfloat16 h; unsigned short u; } cv;
    cv.h = __float2bfloat16(f);
    return cv.u;
}

__device__ __forceinline__ void store_bf4(__hip_bfloat16* p, float a, float b, float c, float d) {
    unsigned long long pk = (unsigned long long)f2b(a)
        | ((unsigned long long)f2b(b) << 16)
        | ((unsigned long long)f2b(c) << 32)
        | ((unsigned long long)f2b(d) << 48);
    *(unsigned long long*)p = pk;
}

__device__ __forceinline__ void gld16(const void* g, void* l) {
    __builtin_amdgcn_global_load_lds(
        (const __attribute__((address_space(1))) unsigned int*)g,
        (__attribute__((address_space(3))) unsigned int*)l,
        16, 0, 0);
}

// ---------------- embedding (dual write f32 + bf16) ----------------
__global__ void embed_k(const int* __restrict__ x, const float* __restrict__ tok,
                        const float* __restrict__ pos, float* __restrict__ h,
                        __hip_bfloat16* __restrict__ hbf) {
    int bs = blockIdx.x;
    int s = bs % S_;
    int t = x[bs];
    for (int d = threadIdx.x; d < D_; d += blockDim.x) {
        float v = tok[(size_t)t * D_ + d] + pos[(size_t)s * D_ + d];
        h[(size_t)bs * D_ + d] = v;
        hbf[(size_t)bs * D_ + d] = __float2bfloat16(v);
    }
}

// ---------------- transpose+convert: src f32 [K][N] -> dst bf16 [N][K] ----------------
// grid: (N/32, K/32, layers); dst row stride = K.
__global__ __launch_bounds__(256) void transp_k(const float* __restrict__ src, size_t sl,
                                                __hip_bfloat16* __restrict__ dst, size_t dl,
                                                int N, int K) {
    const float* S = src + (size_t)blockIdx.z * sl;
    __hip_bfloat16* Dp = dst + (size_t)blockIdx.z * dl;
    __shared__ float T[32][33];
    const int k0 = blockIdx.y * 32, n0 = blockIdx.x * 32;
    const int tid = threadIdx.x;
    const int r = tid >> 3, c4 = (tid & 7) * 4;
    float4 vv = *(const float4*)&S[(size_t)(k0 + r) * N + n0 + c4];
    T[r][c4 + 0] = vv.x; T[r][c4 + 1] = vv.y; T[r][c4 + 2] = vv.z; T[r][c4 + 3] = vv.w;
    __syncthreads();
    store_bf4(&Dp[(size_t)(n0 + r) * K + k0 + c4],
              T[c4 + 0][r], T[c4 + 1][r], T[c4 + 2][r], T[c4 + 3][r]);
}

// ---------------- concat qkv biases: [L][768]x3 -> [L][2304] ----------------
__global__ void bcat_k(const float* __restrict__ bq, const float* __restrict__ bk,
                       const float* __restrict__ bv, float* __restrict__ dst) {
    int l = blockIdx.x;
    for (int j = threadIdx.x; j < D_; j += blockDim.x) {
        dst[(size_t)l * NQKV_ + j]          = bq[(size_t)l * D_ + j];
        dst[(size_t)l * NQKV_ + D_ + j]     = bk[(size_t)l * D_ + j];
        dst[(size_t)l * NQKV_ + 2 * D_ + j] = bv[(size_t)l * D_ + j];
    }
}

// ---------------- f32 -> bf16 vector convert ----------------
__global__ void cvt_k(const float* __restrict__ in, __hip_bfloat16* __restrict__ out, int n) {
    int i = (blockIdx.x * 256 + threadIdx.x) * 4;
    if (i < n) {
        float4 v = *(const float4*)&in[i];
        store_bf4(&out[i], v.x, v.y, v.z, v.w);
    }
}

// ---------------- MFMA bf16 GEMM: C = act(A[M,K] @ Bt[N,K]^T + bias) ----------------
// 256 threads = 4 waves in 2x2; per-wave tile WMxWN; 16x16x32 bf16 MFMA; BK=64.
template<int BM, int BN, int ACT, bool WF32, bool WBF>
__global__ __launch_bounds__(256) void mgemm_k(const __hip_bfloat16* __restrict__ A,
                                               const __hip_bfloat16* __restrict__ Bt,
                                               const float* __restrict__ bias,
                                               float* __restrict__ Cf,
                                               __hip_bfloat16* __restrict__ Cb,
                                               int M, int N, int K) {
    constexpr int WM = BM / 2, WN = BN / 2;
    constexpr int FM = WM / 16, FN = WN / 16;
    __shared__ __hip_bfloat16 Al[BM * 64];
    __shared__ __hip_bfloat16 Bl[BN * 64];
    const int tid = threadIdx.x;
    const int wid = tid >> 6, lane = tid & 63;
    const int wr = wid >> 1, wc = wid & 1;
    const int lrow = lane & 15, kq = lane >> 4;
    const int row0 = blockIdx.y * BM, col0 = blockIdx.x * BN;

    f32x4 acc[FM][FN];
    #pragma unroll
    for (int i = 0; i < FM; ++i)
        #pragma unroll
        for (int j = 0; j < FN; ++j)
            acc[i][j] = (f32x4){0.f, 0.f, 0.f, 0.f};

    const int srow = (lane >> 3);       // staging row within 8-row group
    const int scol = (lane & 7) * 8;    // staging k-offset (elements)

    for (int kk = 0; kk < K; kk += 64) {
        #pragma unroll
        for (int i = 0; i < BM / 32; ++i)
            gld16(A + (size_t)(row0 + i * 32 + wid * 8 + srow) * K + kk + scol,
                  &Al[(i * 32 + wid * 8) * 64]);
        #pragma unroll
        for (int i = 0; i < BN / 32; ++i)
            gld16(Bt + (size_t)(col0 + i * 32 + wid * 8 + srow) * K + kk + scol,
                  &Bl[(i * 32 + wid * 8) * 64]);
        __syncthreads();

        #pragma unroll
        for (int kc = 0; kc < 2; ++kc) {
            short8 af[FM], bfr[FN];
            #pragma unroll
            for (int i = 0; i < FM; ++i)
                af[i] = *(const short8*)&Al[(wr * WM + i * 16 + lrow) * 64 + kc * 32 + kq * 8];
            #pragma unroll
            for (int j = 0; j < FN; ++j)
                bfr[j] = *(const short8*)&Bl[(wc * WN + j * 16 + lrow) * 64 + kc * 32 + kq * 8];
            #pragma unroll
            for (int i = 0; i < FM; ++i)
                #pragma unroll
                for (int j = 0; j < FN; ++j)
                    acc[i][j] = __builtin_amdgcn_mfma_f32_16x16x32_bf16(af[i], bfr[j], acc[i][j], 0, 0, 0);
        }
        __syncthreads();
    }

    #pragma unroll
    for (int i = 0; i < FM; ++i)
        #pragma unroll
        for (int j = 0; j < FN; ++j) {
            const int col = col0 + wc * WN + j * 16 + lrow;
            const float bv = bias[col];
            #pragma unroll
            for (int r = 0; r < 4; ++r) {
                const int row = row0 + wr * WM + i * 16 + kq * 4 + r;
                float vv = acc[i][j][r] + bv;
                if (ACT == 1) vv = 0.5f * vv * (1.0f + erff(vv * 0.70710678118654752f));
                if (WF32) Cf[(size_t)row * N + col] = vv;
                if (WBF)  Cb[(size_t)row * N + col] = __float2bfloat16(vv);
            }
        }
}

// ---------------- legacy f32 GEMM (fallback for logits when no workspace) ----------------
__global__ __launch_bounds__(256) void gemm_k(const float* __restrict__ A,
                                              const float* __restrict__ W,
                                              const float* __restrict__ bias,
                                              float* __restrict__ Cout,
                                              int M, int N, int K) {
    __shared__ float As[64][16];
    __shared__ float Bs[16][64];
    const int tid = threadIdx.x;
    const int tx = tid & 15, ty = tid >> 4;
    const int row0 = blockIdx.y * 64, col0 = blockIdx.x * 64;
    float acc[4][4] = {};

    for (int kk = 0; kk < K; kk += 16) {
        #pragma unroll
        for (int it = 0; it < 4; ++it) {
            int idx = tid + it * 256;
            int m = idx >> 4, k = idx & 15;
            As[m][k] = A[(size_t)(row0 + m) * K + kk + k];
            int r = idx >> 6, c = idx & 63;
            Bs[r][c] = W[(size_t)(kk + r) * N + col0 + c];
        }
        __syncthreads();
        #pragma unroll
        for (int k = 0; k < 16; ++k) {
            float a[4], b[4];
            #pragma unroll
            for (int i = 0; i < 4; ++i) a[i] = As[ty * 4 + i][k];
            #pragma unroll
            for (int j = 0; j < 4; ++j) b[j] = Bs[k][tx * 4 + j];
            #pragma unroll
            for (int i = 0; i < 4; ++i)
                #pragma unroll
                for (int j = 0; j < 4; ++j)
                    acc[i][j] += a[i] * b[j];
        }
        __syncthreads();
    }

    #pragma unroll
    for (int i = 0; i < 4; ++i) {
        int r = row0 + ty * 4 + i;
        #pragma unroll
        for (int j = 0; j < 4; ++j) {
            int c = col0 + tx * 4 + j;
            Cout[(size_t)r * N + c] = acc[i][j] + bias[c];
        }
    }
}

// ---------------- flash attention on fused qkv [M][2304]; bf16 output ----------------
__global__ __launch_bounds__(256) void fattn_k(const float* __restrict__ qkv,
                                               __hip_bfloat16* __restrict__ o) {
    const int qt0 = blockIdx.x * QT_;
    const int bh = blockIdx.y;
    const int b = bh / H_, hh = bh % H_;
    const size_t rb = (size_t)b * S_;
    const int hoff = hh * DH_;

    __shared__ float Qs[QT_][PAD_];
    __shared__ float Ks[KT_][PAD_];
    __shared__ float Vs[KT_][PAD_];
    __shared__ float Ps[QT_][PAD_];

    const int tid = threadIdx.x;
    const int tx = tid & 15;
    const int ty = tid >> 4;
    const int r0 = ty * 2, c0 = tx * 4;

    for (int i = tid; i < QT_ * DH_; i += 256) {
        int r = i >> 6, d = i & 63;
        Qs[r][d] = qkv[(rb + qt0 + r) * NQKV_ + hoff + d] * 0.03608439182435161f;
    }

    float m_i[2] = {-1e30f, -1e30f};
    float l_i[2] = {0.f, 0.f};
    float oacc[2][4] = {};

    for (int kt0 = 0; kt0 < S_; kt0 += KT_) {
        __syncthreads();
        for (int i = tid; i < KT_ * DH_; i += 256) {
            int r = i >> 6, d = i & 63;
            Ks[r][d] = qkv[(rb + kt0 + r) * NQKV_ + D_ + hoff + d];
            Vs[r][d] = qkv[(rb + kt0 + r) * NQKV_ + 2 * D_ + hoff + d];
        }
        __syncthreads();

        float s[2][4] = {};
        #pragma unroll 8
        for (int d = 0; d < DH_; ++d) {
            float q0v = Qs[r0 + 0][d];
            float q1v = Qs[r0 + 1][d];
            float kv0 = Ks[c0 + 0][d];
            float kv1 = Ks[c0 + 1][d];
            float kv2 = Ks[c0 + 2][d];
            float kv3 = Ks[c0 + 3][d];
            s[0][0] += q0v * kv0; s[0][1] += q0v * kv1; s[0][2] += q0v * kv2; s[0][3] += q0v * kv3;
            s[1][0] += q1v * kv0; s[1][1] += q1v * kv1; s[1][2] += q1v * kv2; s[1][3] += q1v * kv3;
        }

        #pragma unroll
        for (int i = 0; i < 2; ++i) {
            float tmax = fmaxf(fmaxf(s[i][0], s[i][1]), fmaxf(s[i][2], s[i][3]));
            #pragma unroll
            for (int off = 1; off <= 8; off <<= 1)
                tmax = fmaxf(tmax, __shfl_xor(tmax, off));
            float mnew = fmaxf(m_i[i], tmax);
            float corr = __expf(m_i[i] - mnew);
            m_i[i] = mnew;
            float psum = 0.f;
            #pragma unroll
            for (int j = 0; j < 4; ++j) {
                float p = __expf(s[i][j] - mnew);
                Ps[r0 + i][c0 + j] = p;
                psum += p;
            }
            #pragma unroll
            for (int off = 1; off <= 8; off <<= 1)
                psum += __shfl_xor(psum, off);
            l_i[i] = l_i[i] * corr + psum;
            #pragma unroll
            for (int j = 0; j < 4; ++j) oacc[i][j] *= corr;
        }
        __syncthreads();

        #pragma unroll 8
        for (int kk = 0; kk < KT_; ++kk) {
            float p0 = Ps[r0 + 0][kk];
            float p1 = Ps[r0 + 1][kk];
            float v0 = Vs[kk][c0 + 0];
            float v1 = Vs[kk][c0 + 1];
            float v2 = Vs[kk][c0 + 2];
            float v3 = Vs[kk][c0 + 3];
            oacc[0][0] += p0 * v0; oacc[0][1] += p0 * v1; oacc[0][2] += p0 * v2; oacc[0][3] += p0 * v3;
            oacc[1][0] += p1 * v0; oacc[1][1] += p1 * v1; oacc[1][2] += p1 * v2; oacc[1][3] += p1 * v3;
        }
    }

    #pragma unroll
    for (int i = 0; i < 2; ++i) {
        float inv = 1.0f / l_i[i];
        store_bf4(&o[(rb + qt0 + r0 + i) * (size_t)D_ + hoff + c0],
                  oacc[i][0] * inv, oacc[i][1] * inv, oacc[i][2] * inv, oacc[i][3] * inv);
    }
}

// ---------------- add + layernorm; dual write f32 (+bf16 when needed) ----------------
__global__ __launch_bounds__(256) void addln_k(const float* __restrict__ a,
                                               const float* __restrict__ b,
                                               const float* __restrict__ g,
                                               const float* __restrict__ beta,
                                               float* __restrict__ out,
                                               __hip_bfloat16* __restrict__ out_bf) {
    const int r = blockIdx.x;
    const int tid = threadIdx.x;
    __shared__ float red[256];
    float xv[3];
    float s = 0.f;
    #pragma unroll
    for (int i = 0; i < 3; ++i) {
        int d = tid + i * 256;
        xv[i] = a[(size_t)r * D_ + d] + b[(size_t)r * D_ + d];
        s += xv[i];
    }
    red[tid] = s; __syncthreads();
    for (int st = 128; st > 0; st >>= 1) { if (tid < st) red[tid] += red[tid + st]; __syncthreads(); }
    float mu = red[0] * (1.0f / D_);
    __syncthreads();
    s = 0.f;
    #pragma unroll
    for (int i = 0; i < 3; ++i) { float dd = xv[i] - mu; s += dd * dd; }
    red[tid] = s; __syncthreads();
    for (int st = 128; st > 0; st >>= 1) { if (tid < st) red[tid] += red[tid + st]; __syncthreads(); }
    float rstd = rsqrtf(red[0] * (1.0f / D_) + 1e-5f);
    #pragma unroll
    for (int i = 0; i < 3; ++i) {
        int d = tid + i * 256;
        float v = (xv[i] - mu) * rstd * g[d] + beta[d];
        out[(size_t)r * D_ + d] = v;
        out_bf[(size_t)r * D_ + d] = __float2bfloat16(v);
    }
}

// ---------------- in-place log-softmax over f32 logits rows ----------------
__global__ __launch_bounds__(256) void lsm_k(float* __restrict__ lp) {
    const int r = blockIdx.x;
    const int tid = threadIdx.x;
    __shared__ float red[256];
    float* row = lp + (size_t)r * V_;
    float m = -1e30f;
    for (int c = tid; c < V_; c += 256) m = fmaxf(m, row[c]);
    red[tid] = m; __syncthreads();
    for (int st = 128; st > 0; st >>= 1) { if (tid < st) red[tid] = fmaxf(red[tid], red[tid + st]); __syncthreads(); }
    m = red[0]; __syncthreads();
    float l = 0.f;
    for (int c = tid; c < V_; c += 256) l += __expf(row[c] - m);
    red[tid] = l; __syncthreads();
    for (int st = 128; st > 0; st >>= 1) { if (tid < st) red[tid] += red[tid + st]; __syncthreads(); }
    float sub = m + __logf(red[0]);
    for (int c = tid; c < V_; c += 256) row[c] = row[c] - sub;
}

extern "C" void kernel_launch(void* const* d_in, const int* in_sizes, int n_in,
                              void* d_out, int out_size, void* d_ws, size_t ws_size,
                              hipStream_t stream) {
    const int*   x    = (const int*)  d_in[0];
    const float* tok  = (const float*)d_in[1];
    const float* pos  = (const float*)d_in[2];
    const float* Wq   = (const float*)d_in[3];
    const float* bq   = (const float*)d_in[4];
    const float* Wk   = (const float*)d_in[5];
    const float* bk   = (const float*)d_in[6];
    const float* Wv   = (const float*)d_in[7];
    const float* bv   = (const float*)d_in[8];
    const float* Wo   = (const float*)d_in[9];
    const float* bo   = (const float*)d_in[10];
    const float* ln1g = (const float*)d_in[11];
    const float* ln1b = (const float*)d_in[12];
    const float* W1   = (const float*)d_in[13];
    const float* b1   = (const float*)d_in[14];
    const float* W2   = (const float*)d_in[15];
    const float* b2   = (const float*)d_in[16];
    const float* ln2g = (const float*)d_in[17];
    const float* ln2b = (const float*)d_in[18];
    const float* Wf   = (const float*)d_in[19];
    const float* bff  = (const float*)d_in[20];

    float* out = (float*)d_out;
    const size_t HS = (size_t)BS_ * D_;              // 1,572,864

    // f32-slot layout inside logits scratch region [0, BS_*V_):
    float* qkv   = out;                              // [0, 4,718,592)
    __hip_bfloat16* att_bf = (__hip_bfloat16*)(out + 4718592);   // 1.57M bf16
    float* tmp   = out + 5505024;
    float* h1    = out + 7077888;
    __hip_bfloat16* h1_bf  = (__hip_bfloat16*)(out + 8650752);
    __hip_bfloat16* ff_bf  = (__hip_bfloat16*)(out + 9437184);   // 6.29M bf16
    __hip_bfloat16* h_bf   = (__hip_bfloat16*)(out + 12582912);
    __hip_bfloat16* Wqkv_t = (__hip_bfloat16*)(out + 13369344);  // 6 x [2304][768]
    __hip_bfloat16* Wo_t   = (__hip_bfloat16*)(out + 18677760);  // 6 x [768][768]
    __hip_bfloat16* W1_t   = (__hip_bfloat16*)(out + 20447232);  // 6 x [3072][768]
    __hip_bfloat16* W2_t   = (__hip_bfloat16*)(out + 27525120);  // 6 x [768][3072]
    float* bqkv  = out + 34603008;                   // 6 x 2304
    float* h     = out + (size_t)BS_ * V_;           // tail: hset output

    const bool ws_ok = ws_size >= (size_t)(24576000ULL * 2 + HS * 2);
    __hip_bfloat16* Wf_t   = (__hip_bfloat16*)d_ws;              // [32000][768]
    __hip_bfloat16* hbf_ws = (__hip_bfloat16*)((char*)d_ws + 49152000);

    // ---- weight transpose/convert pre-pass ----
    const size_t DD = (size_t)D_ * D_, DF = (size_t)D_ * F_;
    const size_t QKVL = (size_t)NQKV_ * D_;
    transp_k<<<dim3(D_/32, D_/32, L_), 256, 0, stream>>>(Wq, DD, Wqkv_t,             QKVL, D_, D_);
    transp_k<<<dim3(D_/32, D_/32, L_), 256, 0, stream>>>(Wk, DD, Wqkv_t + DD,        QKVL, D_, D_);
    transp_k<<<dim3(D_/32, D_/32, L_), 256, 0, stream>>>(Wv, DD, Wqkv_t + 2 * DD,    QKVL, D_, D_);
    transp_k<<<dim3(D_/32, D_/32, L_), 256, 0, stream>>>(Wo, DD, Wo_t,               DD,   D_, D_);
    transp_k<<<dim3(F_/32, D_/32, L_), 256, 0, stream>>>(W1, DF, W1_t,               DF,   F_, D_);
    transp_k<<<dim3(D_/32, F_/32, L_), 256, 0, stream>>>(W2, DF, W2_t,               DF,   D_, F_);
    bcat_k<<<L_, 256, 0, stream>>>(bq, bk, bv, bqkv);
    if (ws_ok)
        transp_k<<<dim3(V_/32, D_/32, 1), 256, 0, stream>>>(Wf, 0, Wf_t, 0, V_, D_);

    embed_k<<<BS_, 256, 0, stream>>>(x, tok, pos, h, h_bf);

    const dim3 gQKV(NQKV_/128, BS_/128);   // (18, 16)
    const dim3 gFF1(F_/128,    BS_/128);   // (24, 16)
    const dim3 gOUT(D_/128,    BS_/64);    // (6, 32) for 64x128 tiles
    const dim3 gA(S_/QT_, B_*H_);          // (32, 24)
    for (int i = 0; i < L_; ++i) {
        mgemm_k<128,128,0,true,false><<<gQKV, 256, 0, stream>>>(
            h_bf, Wqkv_t + (size_t)i * QKVL, bqkv + (size_t)i * NQKV_, qkv, nullptr, BS_, NQKV_, D_);
        fattn_k<<<gA, 256, 0, stream>>>(qkv, att_bf);
        mgemm_k<64,128,0,true,false><<<gOUT, 256, 0, stream>>>(
            att_bf, Wo_t + (size_t)i * DD, bo + (size_t)i * D_, tmp, nullptr, BS_, D_, D_);
        addln_k<<<BS_, 256, 0, stream>>>(tmp, h, ln1g + (size_t)i * D_, ln1b + (size_t)i * D_, h1, h1_bf);
        mgemm_k<128,128,1,false,true><<<gFF1, 256, 0, stream>>>(
            h1_bf, W1_t + (size_t)i * DF, b1 + (size_t)i * F_, nullptr, ff_bf, BS_, F_, D_);
        mgemm_k<64,128,0,true,false><<<gOUT, 256, 0, stream>>>(
            ff_bf, W2_t + (size_t)i * DF, b2 + (size_t)i * D_, tmp, nullptr, BS_, D_, F_);
        addln_k<<<BS_, 256, 0, stream>>>(tmp, h1, ln2g + (size_t)i * D_, ln2b + (size_t)i * D_, h, h_bf);
    }

    if (ws_ok) {
        cvt_k<<<(int)(HS / 1024), 256, 0, stream>>>(h, hbf_ws, (int)HS);
        mgemm_k<128,128,0,true,false><<<dim3(V_/128, BS_/128), 256, 0, stream>>>(
            hbf_ws, Wf_t, bff, out, nullptr, BS_, V_, D_);
    } else {
        gemm_k<<<dim3(V_/64, BS_/64), 256, 0, stream>>>(h, Wf, bff, out, BS_, V_, D_);
    }
    lsm_k<<<BS_, 256, 0, stream>>>(out);
}

// Round 5
// 1616.403 us; speedup vs baseline: 9.5008x; 1.6484x over previous
//
#include <hip/hip_runtime.h>
#include <hip/hip_bf16.h>
#include <math.h>

#define B_ 2
#define S_ 1024
#define V_ 32000
#define D_ 768
#define F_ 3072
#define H_ 12
#define L_ 6
#define DH_ 64
#define BS_ (B_*S_)   // 2048
#define NQKV_ 2304
#define KVB_ 128

typedef __attribute__((ext_vector_type(8))) short short8;
typedef __attribute__((ext_vector_type(4))) float f32x4;

__device__ __forceinline__ unsigned short f2b(float f) {
    union { __hip_bfloat16 h; unsigned short u; } cv;
    cv.h = __float2bfloat16(f);
    return cv.u;
}

__device__ __forceinline__ void store_bf4(__hip_bfloat16* p, float a, float b, float c, float d) {
    unsigned long long pk = (unsigned long long)f2b(a)
        | ((unsigned long long)f2b(b) << 16)
        | ((unsigned long long)f2b(c) << 32)
        | ((unsigned long long)f2b(d) << 48);
    *(unsigned long long*)p = pk;
}

__device__ __forceinline__ void gld16(const void* g, void* l) {
    __builtin_amdgcn_global_load_lds(
        (const __attribute__((address_space(1))) unsigned int*)g,
        (__attribute__((address_space(3))) unsigned int*)l,
        16, 0, 0);
}

// ---------------- embedding (dual write f32 + bf16) ----------------
__global__ void embed_k(const int* __restrict__ x, const float* __restrict__ tok,
                        const float* __restrict__ pos, float* __restrict__ h,
                        __hip_bfloat16* __restrict__ hbf) {
    int bs = blockIdx.x;
    int s = bs % S_;
    int t = x[bs];
    for (int d = threadIdx.x; d < D_; d += blockDim.x) {
        float v = tok[(size_t)t * D_ + d] + pos[(size_t)s * D_ + d];
        h[(size_t)bs * D_ + d] = v;
        hbf[(size_t)bs * D_ + d] = __float2bfloat16(v);
    }
}

// ---------------- transpose+convert: src f32 [K][N] -> dst bf16 [N][K] ----------------
__global__ __launch_bounds__(256) void transp_k(const float* __restrict__ src, size_t sl,
                                                __hip_bfloat16* __restrict__ dst, size_t dl,
                                                int N, int K) {
    const float* S = src + (size_t)blockIdx.z * sl;
    __hip_bfloat16* Dp = dst + (size_t)blockIdx.z * dl;
    __shared__ float T[32][33];
    const int k0 = blockIdx.y * 32, n0 = blockIdx.x * 32;
    const int tid = threadIdx.x;
    const int r = tid >> 3, c4 = (tid & 7) * 4;
    float4 vv = *(const float4*)&S[(size_t)(k0 + r) * N + n0 + c4];
    T[r][c4 + 0] = vv.x; T[r][c4 + 1] = vv.y; T[r][c4 + 2] = vv.z; T[r][c4 + 3] = vv.w;
    __syncthreads();
    store_bf4(&Dp[(size_t)(n0 + r) * K + k0 + c4],
              T[c4 + 0][r], T[c4 + 1][r], T[c4 + 2][r], T[c4 + 3][r]);
}

// ---------------- concat qkv biases ----------------
__global__ void bcat_k(const float* __restrict__ bq, const float* __restrict__ bk,
                       const float* __restrict__ bv, float* __restrict__ dst) {
    int l = blockIdx.x;
    for (int j = threadIdx.x; j < D_; j += blockDim.x) {
        dst[(size_t)l * NQKV_ + j]          = bq[(size_t)l * D_ + j];
        dst[(size_t)l * NQKV_ + D_ + j]     = bk[(size_t)l * D_ + j];
        dst[(size_t)l * NQKV_ + 2 * D_ + j] = bv[(size_t)l * D_ + j];
    }
}

// ---------------- f32 -> bf16 vector convert ----------------
__global__ void cvt_k(const float* __restrict__ in, __hip_bfloat16* __restrict__ out, int n) {
    int i = (blockIdx.x * 256 + threadIdx.x) * 4;
    if (i < n) {
        float4 v = *(const float4*)&in[i];
        store_bf4(&out[i], v.x, v.y, v.z, v.w);
    }
}

// ---------------- MFMA bf16 GEMM: C = act(A[M,K] @ Bt[N,K]^T + bias) ----------------
template<int BM, int BN, int ACT, bool WF32, bool WBF>
__global__ __launch_bounds__(256) void mgemm_k(const __hip_bfloat16* __restrict__ A,
                                               const __hip_bfloat16* __restrict__ Bt,
                                               const float* __restrict__ bias,
                                               float* __restrict__ Cf,
                                               __hip_bfloat16* __restrict__ Cb,
                                               int M, int N, int K) {
    constexpr int WM = BM / 2, WN = BN / 2;
    constexpr int FM = WM / 16, FN = WN / 16;
    __shared__ __hip_bfloat16 Al[BM * 64];
    __shared__ __hip_bfloat16 Bl[BN * 64];
    const int tid = threadIdx.x;
    const int wid = tid >> 6, lane = tid & 63;
    const int wr = wid >> 1, wc = wid & 1;
    const int lrow = lane & 15, kq = lane >> 4;
    const int row0 = blockIdx.y * BM, col0 = blockIdx.x * BN;

    f32x4 acc[FM][FN];
    #pragma unroll
    for (int i = 0; i < FM; ++i)
        #pragma unroll
        for (int j = 0; j < FN; ++j)
            acc[i][j] = (f32x4){0.f, 0.f, 0.f, 0.f};

    const int srow = (lane >> 3);
    const int scol = (lane & 7) * 8;

    for (int kk = 0; kk < K; kk += 64) {
        #pragma unroll
        for (int i = 0; i < BM / 32; ++i)
            gld16(A + (size_t)(row0 + i * 32 + wid * 8 + srow) * K + kk + scol,
                  &Al[(i * 32 + wid * 8) * 64]);
        #pragma unroll
        for (int i = 0; i < BN / 32; ++i)
            gld16(Bt + (size_t)(col0 + i * 32 + wid * 8 + srow) * K + kk + scol,
                  &Bl[(i * 32 + wid * 8) * 64]);
        __syncthreads();

        #pragma unroll
        for (int kc = 0; kc < 2; ++kc) {
            short8 af[FM], bfr[FN];
            #pragma unroll
            for (int i = 0; i < FM; ++i)
                af[i] = *(const short8*)&Al[(wr * WM + i * 16 + lrow) * 64 + kc * 32 + kq * 8];
            #pragma unroll
            for (int j = 0; j < FN; ++j)
                bfr[j] = *(const short8*)&Bl[(wc * WN + j * 16 + lrow) * 64 + kc * 32 + kq * 8];
            #pragma unroll
            for (int i = 0; i < FM; ++i)
                #pragma unroll
                for (int j = 0; j < FN; ++j)
                    acc[i][j] = __builtin_amdgcn_mfma_f32_16x16x32_bf16(af[i], bfr[j], acc[i][j], 0, 0, 0);
        }
        __syncthreads();
    }

    #pragma unroll
    for (int i = 0; i < FM; ++i)
        #pragma unroll
        for (int j = 0; j < FN; ++j) {
            const int col = col0 + wc * WN + j * 16 + lrow;
            const float bv = bias[col];
            #pragma unroll
            for (int r = 0; r < 4; ++r) {
                const int row = row0 + wr * WM + i * 16 + kq * 4 + r;
                float vv = acc[i][j][r] + bv;
                if (ACT == 1) vv = 0.5f * vv * (1.0f + erff(vv * 0.70710678118654752f));
                if (WF32) Cf[(size_t)row * N + col] = vv;
                if (WBF)  Cb[(size_t)row * N + col] = __float2bfloat16(vv);
            }
        }
}

// ---------------- legacy f32 GEMM (fallback for logits if no workspace) ----------------
__global__ __launch_bounds__(256) void gemm_k(const float* __restrict__ A,
                                              const float* __restrict__ W,
                                              const float* __restrict__ bias,
                                              float* __restrict__ Cout,
                                              int M, int N, int K) {
    __shared__ float As[64][16];
    __shared__ float Bs[16][64];
    const int tid = threadIdx.x;
    const int tx = tid & 15, ty = tid >> 4;
    const int row0 = blockIdx.y * 64, col0 = blockIdx.x * 64;
    float acc[4][4] = {};

    for (int kk = 0; kk < K; kk += 16) {
        #pragma unroll
        for (int it = 0; it < 4; ++it) {
            int idx = tid + it * 256;
            int m = idx >> 4, k = idx & 15;
            As[m][k] = A[(size_t)(row0 + m) * K + kk + k];
            int r = idx >> 6, c = idx & 63;
            Bs[r][c] = W[(size_t)(kk + r) * N + col0 + c];
        }
        __syncthreads();
        #pragma unroll
        for (int k = 0; k < 16; ++k) {
            float a[4], b[4];
            #pragma unroll
            for (int i = 0; i < 4; ++i) a[i] = As[ty * 4 + i][k];
            #pragma unroll
            for (int j = 0; j < 4; ++j) b[j] = Bs[k][tx * 4 + j];
            #pragma unroll
            for (int i = 0; i < 4; ++i)
                #pragma unroll
                for (int j = 0; j < 4; ++j)
                    acc[i][j] += a[i] * b[j];
        }
        __syncthreads();
    }

    #pragma unroll
    for (int i = 0; i < 4; ++i) {
        int r = row0 + ty * 4 + i;
        #pragma unroll
        for (int j = 0; j < 4; ++j) {
            int c = col0 + tx * 4 + j;
            Cout[(size_t)r * N + c] = acc[i][j] + bias[c];
        }
    }
}

// ---------------- MFMA flash attention ----------------
// qkv bf16 [BS][2304]. Block = 128 thr (2 waves), 32 q-rows (16/wave); KV tile 128.
// Ks [128][64] bf16 (128B rows), Vt [64][128] (256B rows), Ps [32][128] (256B rows).
// Swizzles: Ks byte^=(((r&7)^((r>>3)&7))<<4); Vt/Ps byte^=((row&15)<<4).
__global__ __launch_bounds__(128) void fattn_k(const __hip_bfloat16* __restrict__ qkv,
                                               __hip_bfloat16* __restrict__ o) {
    const int qt0 = blockIdx.x * 32;
    const int bh = blockIdx.y;
    const int b = bh / H_, hh = bh % H_;
    const size_t rb = (size_t)b * S_;
    const int hoff = hh * DH_;

    __shared__ __hip_bfloat16 Ks[KVB_ * 64];
    __shared__ __hip_bfloat16 Vt[64 * KVB_];
    __shared__ __hip_bfloat16 Ps[32 * KVB_];

    const int tid = threadIdx.x;
    const int w = tid >> 6, lane = tid & 63;
    const int lr = lane & 15, lk = lane >> 4;

    // loop-invariant Q fragments: A[row=lr][d = kc*32 + lk*8 + j]
    short8 aq[2];
    {
        const int qrow = qt0 + w * 16 + lr;
        #pragma unroll
        for (int kc = 0; kc < 2; ++kc)
            aq[kc] = *(const short8*)&qkv[(rb + qrow) * NQKV_ + hoff + kc * 32 + lk * 8];
    }

    f32x4 oacc[4];
    float m_i[4], l_i[4];
    #pragma unroll
    for (int r = 0; r < 4; ++r) {
        oacc[r] = (f32x4){0.f, 0.f, 0.f, 0.f};
        m_i[r] = -1e30f;
        l_i[r] = 0.f;
    }

    for (int kt0 = 0; kt0 < S_; kt0 += KVB_) {
        __syncthreads();                               // prev tile fully consumed
        // ---- stage K [128 k][64 d] ----
        #pragma unroll
        for (int p = 0; p < 8; ++p) {
            int idx = tid + p * 128;
            int r = idx >> 3, cb = (idx & 7) * 16;     // byte col in row
            short8 kv = *(const short8*)&qkv[(rb + kt0 + r) * NQKV_ + D_ + hoff + cb / 2];
            *(short8*)((char*)Ks + r * 128 + (cb ^ ((((r & 7) ^ ((r >> 3) & 7)) << 4)))) = kv;
        }
        // ---- stage V^T [64 d][128 k] ----
        #pragma unroll
        for (int p = 0; p < 4; ++p) {
            int k0 = (tid & 63) * 2;
            int d0 = (tid >> 6) * 8 + p * 16;
            const __hip_bfloat16* vp = &qkv[(rb + kt0 + k0) * NQKV_ + 2 * D_ + hoff + d0];
            short8 va = *(const short8*)vp;
            short8 vb = *(const short8*)(vp + NQKV_);
            #pragma unroll
            for (int j = 0; j < 8; ++j) {
                int d = d0 + j;
                unsigned int pk = (unsigned int)(unsigned short)va[j]
                                | ((unsigned int)(unsigned short)vb[j] << 16);
                *(unsigned int*)((char*)Vt + d * 256 + ((k0 * 2) ^ ((d & 15) << 4))) = pk;
            }
        }
        __syncthreads();                               // tiles ready

        // ---- scores S = Q @ K^T : 8 col-frags x 2 k-steps ----
        f32x4 s[8];
        #pragma unroll
        for (int j = 0; j < 8; ++j) s[j] = (f32x4){0.f, 0.f, 0.f, 0.f};
        #pragma unroll
        for (int kc = 0; kc < 2; ++kc) {
            #pragma unroll
            for (int j = 0; j < 8; ++j) {
                int kr = j * 16 + lr;
                short8 bk = *(const short8*)((const char*)Ks + kr * 128
                              + ((kc * 64 + lk * 16) ^ ((((kr & 7) ^ ((kr >> 3) & 7)) << 4))));
                s[j] = __builtin_amdgcn_mfma_f32_16x16x32_bf16(aq[kc], bk, s[j], 0, 0, 0);
            }
        }
        #pragma unroll
        for (int j = 0; j < 8; ++j)
            #pragma unroll
            for (int r = 0; r < 4; ++r)
                s[j][r] *= 0.03608439182435161f;       // 1/sqrt(768)

        // ---- online softmax (rows = lk*4+r; cols across lr-group) ----
        #pragma unroll
        for (int r = 0; r < 4; ++r) {
            float tmax = s[0][r];
            #pragma unroll
            for (int j = 1; j < 8; ++j) tmax = fmaxf(tmax, s[j][r]);
            #pragma unroll
            for (int off = 1; off <= 8; off <<= 1)
                tmax = fmaxf(tmax, __shfl_xor(tmax, off));
            float mnew = fmaxf(m_i[r], tmax);
            float corr = __expf(m_i[r] - mnew);
            m_i[r] = mnew;
            float psum = 0.f;
            const int prow = w * 16 + lk * 4 + r;
            #pragma unroll
            for (int j = 0; j < 8; ++j) {
                float p = __expf(s[j][r] - mnew);
                psum += p;
                *(__hip_bfloat16*)((char*)Ps + prow * 256
                    + (((j * 16 + lr) * 2) ^ ((prow & 15) << 4))) = __float2bfloat16(p);
            }
            #pragma unroll
            for (int off = 1; off <= 8; off <<= 1)
                psum += __shfl_xor(psum, off);
            l_i[r] = l_i[r] * corr + psum;
            #pragma unroll
            for (int jd = 0; jd < 4; ++jd) oacc[jd][r] *= corr;
        }

        // ---- PV: O += P @ V  (A = Ps rows, B^T = Vt rows; wave-private Ps) ----
        #pragma unroll
        for (int ks = 0; ks < 4; ++ks) {
            const int prow = w * 16 + lr;
            short8 pa = *(const short8*)((const char*)Ps + prow * 256
                          + ((ks * 64 + lk * 16) ^ ((prow & 15) << 4)));
            #pragma unroll
            for (int jd = 0; jd < 4; ++jd) {
                int vr = jd * 16 + lr;
                short8 vb = *(const short8*)((const char*)Vt + vr * 256
                              + ((ks * 64 + lk * 16) ^ ((vr & 15) << 4)));
                oacc[jd] = __builtin_amdgcn_mfma_f32_16x16x32_bf16(pa, vb, oacc[jd], 0, 0, 0);
            }
        }
    }

    #pragma unroll
    for (int r = 0; r < 4; ++r) {
        float inv = 1.0f / l_i[r];
        const int row = qt0 + w * 16 + lk * 4 + r;
        #pragma unroll
        for (int jd = 0; jd < 4; ++jd)
            o[(rb + row) * (size_t)D_ + hoff + jd * 16 + lr] = __float2bfloat16(oacc[jd][r] * inv);
    }
}

// ---------------- add + layernorm; dual write f32 + bf16 ----------------
__global__ __launch_bounds__(256) void addln_k(const float* __restrict__ a,
                                               const float* __restrict__ b,
                                               const float* __restrict__ g,
                                               const float* __restrict__ beta,
                                               float* __restrict__ out,
                                               __hip_bfloat16* __restrict__ out_bf) {
    const int r = blockIdx.x;
    const int tid = threadIdx.x;
    __shared__ float red[256];
    float xv[3];
    float s = 0.f;
    #pragma unroll
    for (int i = 0; i < 3; ++i) {
        int d = tid + i * 256;
        xv[i] = a[(size_t)r * D_ + d] + b[(size_t)r * D_ + d];
        s += xv[i];
    }
    red[tid] = s; __syncthreads();
    for (int st = 128; st > 0; st >>= 1) { if (tid < st) red[tid] += red[tid + st]; __syncthreads(); }
    float mu = red[0] * (1.0f / D_);
    __syncthreads();
    s = 0.f;
    #pragma unroll
    for (int i = 0; i < 3; ++i) { float dd = xv[i] - mu; s += dd * dd; }
    red[tid] = s; __syncthreads();
    for (int st = 128; st > 0; st >>= 1) { if (tid < st) red[tid] += red[tid + st]; __syncthreads(); }
    float rstd = rsqrtf(red[0] * (1.0f / D_) + 1e-5f);
    #pragma unroll
    for (int i = 0; i < 3; ++i) {
        int d = tid + i * 256;
        float v = (xv[i] - mu) * rstd * g[d] + beta[d];
        out[(size_t)r * D_ + d] = v;
        out_bf[(size_t)r * D_ + d] = __float2bfloat16(v);
    }
}

// ---------------- in-place log-softmax over f32 logits rows ----------------
__global__ __launch_bounds__(256) void lsm_k(float* __restrict__ lp) {
    const int r = blockIdx.x;
    const int tid = threadIdx.x;
    __shared__ float red[256];
    float* row = lp + (size_t)r * V_;
    float m = -1e30f;
    for (int c = tid; c < V_; c += 256) m = fmaxf(m, row[c]);
    red[tid] = m; __syncthreads();
    for (int st = 128; st > 0; st >>= 1) { if (tid < st) red[tid] = fmaxf(red[tid], red[tid + st]); __syncthreads(); }
    m = red[0]; __syncthreads();
    float l = 0.f;
    for (int c = tid; c < V_; c += 256) l += __expf(row[c] - m);
    red[tid] = l; __syncthreads();
    for (int st = 128; st > 0; st >>= 1) { if (tid < st) red[tid] += red[tid + st]; __syncthreads(); }
    float sub = m + __logf(red[0]);
    for (int c = tid; c < V_; c += 256) row[c] = row[c] - sub;
}

extern "C" void kernel_launch(void* const* d_in, const int* in_sizes, int n_in,
                              void* d_out, int out_size, void* d_ws, size_t ws_size,
                              hipStream_t stream) {
    const int*   x    = (const int*)  d_in[0];
    const float* tok  = (const float*)d_in[1];
    const float* pos  = (const float*)d_in[2];
    const float* Wq   = (const float*)d_in[3];
    const float* bq   = (const float*)d_in[4];
    const float* Wk   = (const float*)d_in[5];
    const float* bk   = (const float*)d_in[6];
    const float* Wv   = (const float*)d_in[7];
    const float* bv   = (const float*)d_in[8];
    const float* Wo   = (const float*)d_in[9];
    const float* bo   = (const float*)d_in[10];
    const float* ln1g = (const float*)d_in[11];
    const float* ln1b = (const float*)d_in[12];
    const float* W1   = (const float*)d_in[13];
    const float* b1   = (const float*)d_in[14];
    const float* W2   = (const float*)d_in[15];
    const float* b2   = (const float*)d_in[16];
    const float* ln2g = (const float*)d_in[17];
    const float* ln2b = (const float*)d_in[18];
    const float* Wf   = (const float*)d_in[19];
    const float* bff  = (const float*)d_in[20];

    float* out = (float*)d_out;
    const size_t HS = (size_t)BS_ * D_;              // 1,572,864

    // f32-slot layout inside logits scratch region [0, BS_*V_):
    __hip_bfloat16* qkv_bf = (__hip_bfloat16*)out;               // BS*2304 bf16 = 2.36M f32 slots
    __hip_bfloat16* att_bf = (__hip_bfloat16*)(out + 4718592);
    float* tmp   = out + 5505024;
    float* h1    = out + 7077888;
    __hip_bfloat16* h1_bf  = (__hip_bfloat16*)(out + 8650752);
    __hip_bfloat16* ff_bf  = (__hip_bfloat16*)(out + 9437184);
    __hip_bfloat16* h_bf   = (__hip_bfloat16*)(out + 12582912);
    __hip_bfloat16* Wqkv_t = (__hip_bfloat16*)(out + 13369344);  // 6 x [2304][768]
    __hip_bfloat16* Wo_t   = (__hip_bfloat16*)(out + 18677760);  // 6 x [768][768]
    __hip_bfloat16* W1_t   = (__hip_bfloat16*)(out + 20447232);  // 6 x [3072][768]
    __hip_bfloat16* W2_t   = (__hip_bfloat16*)(out + 27525120);  // 6 x [768][3072]
    float* bqkv  = out + 34603008;                   // 6 x 2304
    float* h     = out + (size_t)BS_ * V_;           // tail: hset output

    const bool ws_ok = ws_size >= (size_t)(24576000ULL * 2 + HS * 2);
    __hip_bfloat16* Wf_t   = (__hip_bfloat16*)d_ws;              // [32000][768]
    __hip_bfloat16* hbf_ws = (__hip_bfloat16*)((char*)d_ws + 49152000);

    // ---- weight transpose/convert pre-pass ----
    const size_t DD = (size_t)D_ * D_, DF = (size_t)D_ * F_;
    const size_t QKVL = (size_t)NQKV_ * D_;
    transp_k<<<dim3(D_/32, D_/32, L_), 256, 0, stream>>>(Wq, DD, Wqkv_t,          QKVL, D_, D_);
    transp_k<<<dim3(D_/32, D_/32, L_), 256, 0, stream>>>(Wk, DD, Wqkv_t + DD,     QKVL, D_, D_);
    transp_k<<<dim3(D_/32, D_/32, L_), 256, 0, stream>>>(Wv, DD, Wqkv_t + 2 * DD, QKVL, D_, D_);
    transp_k<<<dim3(D_/32, D_/32, L_), 256, 0, stream>>>(Wo, DD, Wo_t,            DD,   D_, D_);
    transp_k<<<dim3(F_/32, D_/32, L_), 256, 0, stream>>>(W1, DF, W1_t,            DF,   F_, D_);
    transp_k<<<dim3(D_/32, F_/32, L_), 256, 0, stream>>>(W2, DF, W2_t,            DF,   D_, F_);
    bcat_k<<<L_, 256, 0, stream>>>(bq, bk, bv, bqkv);
    if (ws_ok)
        transp_k<<<dim3(V_/32, D_/32, 1), 256, 0, stream>>>(Wf, 0, Wf_t, 0, V_, D_);

    embed_k<<<BS_, 256, 0, stream>>>(x, tok, pos, h, h_bf);

    const dim3 gQKV(NQKV_/128, BS_/128);   // (18, 16)
    const dim3 gFF1(F_/128,    BS_/128);   // (24, 16)
    const dim3 gOUT(D_/128,    BS_/64);    // (6, 32)
    const dim3 gA(S_/32, B_*H_);           // (32, 24)
    for (int i = 0; i < L_; ++i) {
        mgemm_k<128,128,0,false,true><<<gQKV, 256, 0, stream>>>(
            h_bf, Wqkv_t + (size_t)i * QKVL, bqkv + (size_t)i * NQKV_, nullptr, qkv_bf, BS_, NQKV_, D_);
        fattn_k<<<gA, 128, 0, stream>>>(qkv_bf, att_bf);
        mgemm_k<64,128,0,true,false><<<gOUT, 256, 0, stream>>>(
            att_bf, Wo_t + (size_t)i * DD, bo + (size_t)i * D_, tmp, nullptr, BS_, D_, D_);
        addln_k<<<BS_, 256, 0, stream>>>(tmp, h, ln1g + (size_t)i * D_, ln1b + (size_t)i * D_, h1, h1_bf);
        mgemm_k<128,128,1,false,true><<<gFF1, 256, 0, stream>>>(
            h1_bf, W1_t + (size_t)i * DF, b1 + (size_t)i * F_, nullptr, ff_bf, BS_, F_, D_);
        mgemm_k<64,128,0,true,false><<<gOUT, 256, 0, stream>>>(
            ff_bf, W2_t + (size_t)i * DF, b2 + (size_t)i * D_, tmp, nullptr, BS_, D_, F_);
        addln_k<<<BS_, 256, 0, stream>>>(tmp, h1, ln2g + (size_t)i * D_, ln2b + (size_t)i * D_, h, h_bf);
    }

    if (ws_ok) {
        cvt_k<<<(int)(HS / 1024), 256, 0, stream>>>(h, hbf_ws, (int)HS);
        mgemm_k<128,128,0,true,false><<<dim3(V_/128, BS_/128), 256, 0, stream>>>(
            hbf_ws, Wf_t, bff, out, nullptr, BS_, V_, D_);
    } else {
        gemm_k<<<dim3(V_/64, BS_/64), 256, 0, stream>>>(h, Wf, bff, out, BS_, V_, D_);
    }
    lsm_k<<<BS_, 256, 0, stream>>>(out);
}

// Round 6
// 1464.744 us; speedup vs baseline: 10.4845x; 1.1035x over previous
//
#include <hip/hip_runtime.h>
#include <hip/hip_bf16.h>
#include <math.h>

#define B_ 2
#define S_ 1024
#define V_ 32000
#define D_ 768
#define F_ 3072
#define H_ 12
#define L_ 6
#define DH_ 64
#define BS_ (B_*S_)   // 2048
#define NQKV_ 2304
#define KVB_ 128

typedef __attribute__((ext_vector_type(8))) short short8;
typedef __attribute__((ext_vector_type(4))) float f32x4;

__device__ __forceinline__ unsigned short f2b(float f) {
    union { __hip_bfloat16 h; unsigned short u; } cv;
    cv.h = __float2bfloat16(f);
    return cv.u;
}

__device__ __forceinline__ void store_bf4(__hip_bfloat16* p, float a, float b, float c, float d) {
    unsigned long long pk = (unsigned long long)f2b(a)
        | ((unsigned long long)f2b(b) << 16)
        | ((unsigned long long)f2b(c) << 32)
        | ((unsigned long long)f2b(d) << 48);
    *(unsigned long long*)p = pk;
}

__device__ __forceinline__ void gld16(const void* g, void* l) {
    __builtin_amdgcn_global_load_lds(
        (const __attribute__((address_space(1))) unsigned int*)g,
        (__attribute__((address_space(3))) unsigned int*)l,
        16, 0, 0);
}

// ---------------- embedding (dual write f32 + bf16) ----------------
__global__ void embed_k(const int* __restrict__ x, const float* __restrict__ tok,
                        const float* __restrict__ pos, float* __restrict__ h,
                        __hip_bfloat16* __restrict__ hbf) {
    int bs = blockIdx.x;
    int s = bs % S_;
    int t = x[bs];
    for (int d = threadIdx.x; d < D_; d += blockDim.x) {
        float v = tok[(size_t)t * D_ + d] + pos[(size_t)s * D_ + d];
        h[(size_t)bs * D_ + d] = v;
        hbf[(size_t)bs * D_ + d] = __float2bfloat16(v);
    }
}

// ---------------- transpose+convert: src f32 [K][N] -> dst bf16 [N][K] ----------------
__global__ __launch_bounds__(256) void transp_k(const float* __restrict__ src, size_t sl,
                                                __hip_bfloat16* __restrict__ dst, size_t dl,
                                                int N, int K) {
    const float* S = src + (size_t)blockIdx.z * sl;
    __hip_bfloat16* Dp = dst + (size_t)blockIdx.z * dl;
    __shared__ float T[32][33];
    const int k0 = blockIdx.y * 32, n0 = blockIdx.x * 32;
    const int tid = threadIdx.x;
    const int r = tid >> 3, c4 = (tid & 7) * 4;
    float4 vv = *(const float4*)&S[(size_t)(k0 + r) * N + n0 + c4];
    T[r][c4 + 0] = vv.x; T[r][c4 + 1] = vv.y; T[r][c4 + 2] = vv.z; T[r][c4 + 3] = vv.w;
    __syncthreads();
    store_bf4(&Dp[(size_t)(n0 + r) * K + k0 + c4],
              T[c4 + 0][r], T[c4 + 1][r], T[c4 + 2][r], T[c4 + 3][r]);
}

// ---------------- concat qkv biases ----------------
__global__ void bcat_k(const float* __restrict__ bq, const float* __restrict__ bk,
                       const float* __restrict__ bv, float* __restrict__ dst) {
    int l = blockIdx.x;
    for (int j = threadIdx.x; j < D_; j += blockDim.x) {
        dst[(size_t)l * NQKV_ + j]          = bq[(size_t)l * D_ + j];
        dst[(size_t)l * NQKV_ + D_ + j]     = bk[(size_t)l * D_ + j];
        dst[(size_t)l * NQKV_ + 2 * D_ + j] = bv[(size_t)l * D_ + j];
    }
}

// ---------------- f32 -> bf16 vector convert ----------------
__global__ void cvt_k(const float* __restrict__ in, __hip_bfloat16* __restrict__ out, int n) {
    int i = (blockIdx.x * 256 + threadIdx.x) * 4;
    if (i < n) {
        float4 v = *(const float4*)&in[i];
        store_bf4(&out[i], v.x, v.y, v.z, v.w);
    }
}

// ---------------- V transpose: qkv[BS][2304] v-cols -> vT[bh][d][s] ----------------
// grid (S/32, B*H), 256 thr; thread: sc = tid&3 (8-s chunk), d = tid>>2.
__global__ __launch_bounds__(256) void vtr_k(const __hip_bfloat16* __restrict__ qkv,
                                             __hip_bfloat16* __restrict__ vT) {
    const int s0 = blockIdx.x * 32;
    const int bh = blockIdx.y;
    const int b = bh / H_, hh = bh % H_;
    const size_t rb = (size_t)b * S_;
    const int tid = threadIdx.x;
    const int sc = tid & 3, d = tid >> 2;
    const short* src = (const short*)qkv + (rb + s0 + sc * 8) * (size_t)NQKV_ + 2 * D_ + hh * DH_ + d;
    short8 pk;
    #pragma unroll
    for (int i = 0; i < 8; ++i) pk[i] = src[(size_t)i * NQKV_];
    *(short8*)&vT[((size_t)bh * DH_ + d) * S_ + s0 + sc * 8] = pk;
}

// ---------------- MFMA bf16 GEMM: C = act(A[M,K] @ Bt[N,K]^T + bias) ----------------
// SW swaps grid axes (M on blockIdx.x) for weight-panel L2/L3 reuse on wide-N GEMMs.
template<int BM, int BN, int ACT, bool WF32, bool WBF, bool SW>
__global__ __launch_bounds__(256) void mgemm_k(const __hip_bfloat16* __restrict__ A,
                                               const __hip_bfloat16* __restrict__ Bt,
                                               const float* __restrict__ bias,
                                               float* __restrict__ Cf,
                                               __hip_bfloat16* __restrict__ Cb,
                                               int M, int N, int K) {
    constexpr int WM = BM / 2, WN = BN / 2;
    constexpr int FM = WM / 16, FN = WN / 16;
    __shared__ __hip_bfloat16 Al[BM * 64];
    __shared__ __hip_bfloat16 Bl[BN * 64];
    const int tid = threadIdx.x;
    const int wid = tid >> 6, lane = tid & 63;
    const int wr = wid >> 1, wc = wid & 1;
    const int lrow = lane & 15, kq = lane >> 4;
    const int row0 = (SW ? blockIdx.x : blockIdx.y) * BM;
    const int col0 = (SW ? blockIdx.y : blockIdx.x) * BN;

    f32x4 acc[FM][FN];
    #pragma unroll
    for (int i = 0; i < FM; ++i)
        #pragma unroll
        for (int j = 0; j < FN; ++j)
            acc[i][j] = (f32x4){0.f, 0.f, 0.f, 0.f};

    const int srow = (lane >> 3);
    const int scol = (lane & 7) * 8;

    for (int kk = 0; kk < K; kk += 64) {
        #pragma unroll
        for (int i = 0; i < BM / 32; ++i)
            gld16(A + (size_t)(row0 + i * 32 + wid * 8 + srow) * K + kk + scol,
                  &Al[(i * 32 + wid * 8) * 64]);
        #pragma unroll
        for (int i = 0; i < BN / 32; ++i)
            gld16(Bt + (size_t)(col0 + i * 32 + wid * 8 + srow) * K + kk + scol,
                  &Bl[(i * 32 + wid * 8) * 64]);
        __syncthreads();

        #pragma unroll
        for (int kc = 0; kc < 2; ++kc) {
            short8 af[FM], bfr[FN];
            #pragma unroll
            for (int i = 0; i < FM; ++i)
                af[i] = *(const short8*)&Al[(wr * WM + i * 16 + lrow) * 64 + kc * 32 + kq * 8];
            #pragma unroll
            for (int j = 0; j < FN; ++j)
                bfr[j] = *(const short8*)&Bl[(wc * WN + j * 16 + lrow) * 64 + kc * 32 + kq * 8];
            #pragma unroll
            for (int i = 0; i < FM; ++i)
                #pragma unroll
                for (int j = 0; j < FN; ++j)
                    acc[i][j] = __builtin_amdgcn_mfma_f32_16x16x32_bf16(af[i], bfr[j], acc[i][j], 0, 0, 0);
        }
        __syncthreads();
    }

    #pragma unroll
    for (int i = 0; i < FM; ++i)
        #pragma unroll
        for (int j = 0; j < FN; ++j) {
            const int col = col0 + wc * WN + j * 16 + lrow;
            const float bv = bias[col];
            #pragma unroll
            for (int r = 0; r < 4; ++r) {
                const int row = row0 + wr * WM + i * 16 + kq * 4 + r;
                float vv = acc[i][j][r] + bv;
                if (ACT == 1) vv = 0.5f * vv * (1.0f + erff(vv * 0.70710678118654752f));
                if (WF32) Cf[(size_t)row * N + col] = vv;
                if (WBF)  Cb[(size_t)row * N + col] = __float2bfloat16(vv);
            }
        }
}

// ---------------- legacy f32 GEMM (fallback for logits if no workspace) ----------------
__global__ __launch_bounds__(256) void gemm_k(const float* __restrict__ A,
                                              const float* __restrict__ W,
                                              const float* __restrict__ bias,
                                              float* __restrict__ Cout,
                                              int M, int N, int K) {
    __shared__ float As[64][16];
    __shared__ float Bs[16][64];
    const int tid = threadIdx.x;
    const int tx = tid & 15, ty = tid >> 4;
    const int row0 = blockIdx.y * 64, col0 = blockIdx.x * 64;
    float acc[4][4] = {};

    for (int kk = 0; kk < K; kk += 16) {
        #pragma unroll
        for (int it = 0; it < 4; ++it) {
            int idx = tid + it * 256;
            int m = idx >> 4, k = idx & 15;
            As[m][k] = A[(size_t)(row0 + m) * K + kk + k];
            int r = idx >> 6, c = idx & 63;
            Bs[r][c] = W[(size_t)(kk + r) * N + col0 + c];
        }
        __syncthreads();
        #pragma unroll
        for (int k = 0; k < 16; ++k) {
            float a[4], b[4];
            #pragma unroll
            for (int i = 0; i < 4; ++i) a[i] = As[ty * 4 + i][k];
            #pragma unroll
            for (int j = 0; j < 4; ++j) b[j] = Bs[k][tx * 4 + j];
            #pragma unroll
            for (int i = 0; i < 4; ++i)
                #pragma unroll
                for (int j = 0; j < 4; ++j)
                    acc[i][j] += a[i] * b[j];
        }
        __syncthreads();
    }

    #pragma unroll
    for (int i = 0; i < 4; ++i) {
        int r = row0 + ty * 4 + i;
        #pragma unroll
        for (int j = 0; j < 4; ++j) {
            int c = col0 + tx * 4 + j;
            Cout[(size_t)r * N + c] = acc[i][j] + bias[c];
        }
    }
}

// ---------------- MFMA flash attention ----------------
// Q,K from qkv [BS][2304]; V from vT [bh][d][s]. Block = 128 thr (2 waves),
// 32 q-rows; KV tile 128. Ks [128][64] swz byte^=(((r&7)^((r>>3)&7))<<4);
// Vt [64][128] and Ps [32][128] swz byte^=((row&15)<<4).
// K/V staged via global_load_lds with pre-swizzled SOURCE chunks (linear LDS dest).
__global__ __launch_bounds__(128) void fattn_k(const __hip_bfloat16* __restrict__ qkv,
                                               const __hip_bfloat16* __restrict__ vT,
                                               __hip_bfloat16* __restrict__ o) {
    const int qt0 = blockIdx.x * 32;
    const int bh = blockIdx.y;
    const int b = bh / H_, hh = bh % H_;
    const size_t rb = (size_t)b * S_;
    const int hoff = hh * DH_;

    __shared__ __hip_bfloat16 Ks[KVB_ * 64];
    __shared__ __hip_bfloat16 Vt[64 * KVB_];
    __shared__ __hip_bfloat16 Ps[32 * KVB_];

    const int tid = threadIdx.x;
    const int w = tid >> 6, lane = tid & 63;
    const int lr = lane & 15, lk = lane >> 4;

    short8 aq[2];
    {
        const int qrow = qt0 + w * 16 + lr;
        #pragma unroll
        for (int kc = 0; kc < 2; ++kc)
            aq[kc] = *(const short8*)&qkv[(rb + qrow) * NQKV_ + hoff + kc * 32 + lk * 8];
    }

    f32x4 oacc[4];
    float m_i[4], l_i[4];
    #pragma unroll
    for (int r = 0; r < 4; ++r) {
        oacc[r] = (f32x4){0.f, 0.f, 0.f, 0.f};
        m_i[r] = -1e30f;
        l_i[r] = 0.f;
    }

    const size_t vbase = (size_t)bh * DH_ * S_;

    for (int kt0 = 0; kt0 < S_; kt0 += KVB_) {
        __syncthreads();                               // prev tile fully consumed
        // ---- stage K: 8 x gld16 per wave; lane -> row r0+(l>>3), chunk l&7 ----
        #pragma unroll
        for (int t = 0; t < 8; ++t) {
            const int r0 = w * 64 + t * 8;
            const int r = r0 + (lane >> 3);
            const int cs = (lane & 7) ^ ((r & 7) ^ ((r >> 3) & 7));
            gld16(&qkv[(rb + kt0 + r) * NQKV_ + D_ + hoff + cs * 8], &Ks[r0 * 64]);
        }
        // ---- stage V^T: 8 x gld16 per wave; lane -> row d0+(l>>4), chunk l&15 ----
        #pragma unroll
        for (int t = 0; t < 8; ++t) {
            const int d0 = w * 32 + t * 4;
            const int d = d0 + (lane >> 4);
            const int cs = (lane & 15) ^ (d & 15);
            gld16(&vT[vbase + (size_t)d * S_ + kt0 + cs * 8], &Vt[d0 * 128]);
        }
        __syncthreads();                               // tiles ready (drains vmcnt)

        // ---- scores S = Q @ K^T ----
        f32x4 s[8];
        #pragma unroll
        for (int j = 0; j < 8; ++j) s[j] = (f32x4){0.f, 0.f, 0.f, 0.f};
        __builtin_amdgcn_s_setprio(1);
        #pragma unroll
        for (int kc = 0; kc < 2; ++kc) {
            #pragma unroll
            for (int j = 0; j < 8; ++j) {
                int kr = j * 16 + lr;
                short8 bk = *(const short8*)((const char*)Ks + kr * 128
                              + ((kc * 64 + lk * 16) ^ ((((kr & 7) ^ ((kr >> 3) & 7)) << 4))));
                s[j] = __builtin_amdgcn_mfma_f32_16x16x32_bf16(aq[kc], bk, s[j], 0, 0, 0);
            }
        }
        __builtin_amdgcn_s_setprio(0);
        #pragma unroll
        for (int j = 0; j < 8; ++j)
            #pragma unroll
            for (int r = 0; r < 4; ++r)
                s[j][r] *= 0.03608439182435161f;       // 1/sqrt(768)

        // ---- online softmax (rows = lk*4+r; cols across lr-group) ----
        #pragma unroll
        for (int r = 0; r < 4; ++r) {
            float tmax = s[0][r];
            #pragma unroll
            for (int j = 1; j < 8; ++j) tmax = fmaxf(tmax, s[j][r]);
            #pragma unroll
            for (int off = 1; off <= 8; off <<= 1)
                tmax = fmaxf(tmax, __shfl_xor(tmax, off));
            float mnew = fmaxf(m_i[r], tmax);
            float corr = __expf(m_i[r] - mnew);
            m_i[r] = mnew;
            float psum = 0.f;
            const int prow = w * 16 + lk * 4 + r;
            #pragma unroll
            for (int j = 0; j < 8; ++j) {
                float p = __expf(s[j][r] - mnew);
                psum += p;
                *(__hip_bfloat16*)((char*)Ps + prow * 256
                    + (((j * 16 + lr) * 2) ^ ((prow & 15) << 4))) = __float2bfloat16(p);
            }
            #pragma unroll
            for (int off = 1; off <= 8; off <<= 1)
                psum += __shfl_xor(psum, off);
            l_i[r] = l_i[r] * corr + psum;
            #pragma unroll
            for (int jd = 0; jd < 4; ++jd) oacc[jd][r] *= corr;
        }

        // ---- PV: O += P @ V (wave-private Ps) ----
        __builtin_amdgcn_s_setprio(1);
        #pragma unroll
        for (int ks = 0; ks < 4; ++ks) {
            const int prow = w * 16 + lr;
            short8 pa = *(const short8*)((const char*)Ps + prow * 256
                          + ((ks * 64 + lk * 16) ^ ((prow & 15) << 4)));
            #pragma unroll
            for (int jd = 0; jd < 4; ++jd) {
                int vr = jd * 16 + lr;
                short8 vb = *(const short8*)((const char*)Vt + vr * 256
                              + ((ks * 64 + lk * 16) ^ ((vr & 15) << 4)));
                oacc[jd] = __builtin_amdgcn_mfma_f32_16x16x32_bf16(pa, vb, oacc[jd], 0, 0, 0);
            }
        }
        __builtin_amdgcn_s_setprio(0);
    }

    #pragma unroll
    for (int r = 0; r < 4; ++r) {
        float inv = 1.0f / l_i[r];
        const int row = qt0 + w * 16 + lk * 4 + r;
        #pragma unroll
        for (int jd = 0; jd < 4; ++jd)
            o[(rb + row) * (size_t)D_ + hoff + jd * 16 + lr] = __float2bfloat16(oacc[jd][r] * inv);
    }
}

// ---------------- add + layernorm; dual write f32 + bf16 ----------------
__global__ __launch_bounds__(256) void addln_k(const float* __restrict__ a,
                                               const float* __restrict__ b,
                                               const float* __restrict__ g,
                                               const float* __restrict__ beta,
                                               float* __restrict__ out,
                                               __hip_bfloat16* __restrict__ out_bf) {
    const int r = blockIdx.x;
    const int tid = threadIdx.x;
    __shared__ float red[256];
    float xv[3];
    float s = 0.f;
    #pragma unroll
    for (int i = 0; i < 3; ++i) {
        int d = tid + i * 256;
        xv[i] = a[(size_t)r * D_ + d] + b[(size_t)r * D_ + d];
        s += xv[i];
    }
    red[tid] = s; __syncthreads();
    for (int st = 128; st > 0; st >>= 1) { if (tid < st) red[tid] += red[tid + st]; __syncthreads(); }
    float mu = red[0] * (1.0f / D_);
    __syncthreads();
    s = 0.f;
    #pragma unroll
    for (int i = 0; i < 3; ++i) { float dd = xv[i] - mu; s += dd * dd; }
    red[tid] = s; __syncthreads();
    for (int st = 128; st > 0; st >>= 1) { if (tid < st) red[tid] += red[tid + st]; __syncthreads(); }
    float rstd = rsqrtf(red[0] * (1.0f / D_) + 1e-5f);
    #pragma unroll
    for (int i = 0; i < 3; ++i) {
        int d = tid + i * 256;
        float v = (xv[i] - mu) * rstd * g[d] + beta[d];
        out[(size_t)r * D_ + d] = v;
        out_bf[(size_t)r * D_ + d] = __float2bfloat16(v);
    }
}

// ---------------- in-place log-softmax over f32 logits rows (float4) ----------------
__global__ __launch_bounds__(256) void lsm_k(float* __restrict__ lp) {
    const int r = blockIdx.x;
    const int tid = threadIdx.x;
    __shared__ float red[256];
    float* row = lp + (size_t)r * V_;
    float m = -1e30f;
    for (int i = tid * 4; i < V_; i += 1024) {
        float4 v = *(const float4*)&row[i];
        m = fmaxf(m, fmaxf(fmaxf(v.x, v.y), fmaxf(v.z, v.w)));
    }
    red[tid] = m; __syncthreads();
    for (int st = 128; st > 0; st >>= 1) { if (tid < st) red[tid] = fmaxf(red[tid], red[tid + st]); __syncthreads(); }
    m = red[0]; __syncthreads();
    float l = 0.f;
    for (int i = tid * 4; i < V_; i += 1024) {
        float4 v = *(const float4*)&row[i];
        l += __expf(v.x - m) + __expf(v.y - m) + __expf(v.z - m) + __expf(v.w - m);
    }
    red[tid] = l; __syncthreads();
    for (int st = 128; st > 0; st >>= 1) { if (tid < st) red[tid] += red[tid + st]; __syncthreads(); }
    float sub = m + __logf(red[0]);
    for (int i = tid * 4; i < V_; i += 1024) {
        float4 v = *(const float4*)&row[i];
        v.x -= sub; v.y -= sub; v.z -= sub; v.w -= sub;
        *(float4*)&row[i] = v;
    }
}

extern "C" void kernel_launch(void* const* d_in, const int* in_sizes, int n_in,
                              void* d_out, int out_size, void* d_ws, size_t ws_size,
                              hipStream_t stream) {
    const int*   x    = (const int*)  d_in[0];
    const float* tok  = (const float*)d_in[1];
    const float* pos  = (const float*)d_in[2];
    const float* Wq   = (const float*)d_in[3];
    const float* bq   = (const float*)d_in[4];
    const float* Wk   = (const float*)d_in[5];
    const float* bk   = (const float*)d_in[6];
    const float* Wv   = (const float*)d_in[7];
    const float* bv   = (const float*)d_in[8];
    const float* Wo   = (const float*)d_in[9];
    const float* bo   = (const float*)d_in[10];
    const float* ln1g = (const float*)d_in[11];
    const float* ln1b = (const float*)d_in[12];
    const float* W1   = (const float*)d_in[13];
    const float* b1   = (const float*)d_in[14];
    const float* W2   = (const float*)d_in[15];
    const float* b2   = (const float*)d_in[16];
    const float* ln2g = (const float*)d_in[17];
    const float* ln2b = (const float*)d_in[18];
    const float* Wf   = (const float*)d_in[19];
    const float* bff  = (const float*)d_in[20];

    float* out = (float*)d_out;
    const size_t HS = (size_t)BS_ * D_;              // 1,572,864

    // f32-slot layout inside logits scratch region [0, BS_*V_):
    __hip_bfloat16* qkv_bf = (__hip_bfloat16*)out;               // BS*2304 bf16 -> 2,359,296 f32
    __hip_bfloat16* vT     = (__hip_bfloat16*)(out + 2359296);   // BS*768 bf16 (0.79M f32)
    __hip_bfloat16* att_bf = (__hip_bfloat16*)(out + 4718592);
    float* tmp   = out + 5505024;
    float* h1    = out + 7077888;
    __hip_bfloat16* h1_bf  = (__hip_bfloat16*)(out + 8650752);
    __hip_bfloat16* ff_bf  = (__hip_bfloat16*)(out + 9437184);
    __hip_bfloat16* h_bf   = (__hip_bfloat16*)(out + 12582912);
    __hip_bfloat16* Wqkv_t = (__hip_bfloat16*)(out + 13369344);  // 6 x [2304][768]
    __hip_bfloat16* Wo_t   = (__hip_bfloat16*)(out + 18677760);  // 6 x [768][768]
    __hip_bfloat16* W1_t   = (__hip_bfloat16*)(out + 20447232);  // 6 x [3072][768]
    __hip_bfloat16* W2_t   = (__hip_bfloat16*)(out + 27525120);  // 6 x [768][3072]
    float* bqkv  = out + 34603008;                   // 6 x 2304
    float* h     = out + (size_t)BS_ * V_;           // tail: hset output

    const bool ws_ok = ws_size >= (size_t)(24576000ULL * 2 + HS * 2);
    __hip_bfloat16* Wf_t   = (__hip_bfloat16*)d_ws;              // [32000][768]
    __hip_bfloat16* hbf_ws = (__hip_bfloat16*)((char*)d_ws + 49152000);

    // ---- weight transpose/convert pre-pass ----
    const size_t DD = (size_t)D_ * D_, DF = (size_t)D_ * F_;
    const size_t QKVL = (size_t)NQKV_ * D_;
    transp_k<<<dim3(D_/32, D_/32, L_), 256, 0, stream>>>(Wq, DD, Wqkv_t,          QKVL, D_, D_);
    transp_k<<<dim3(D_/32, D_/32, L_), 256, 0, stream>>>(Wk, DD, Wqkv_t + DD,     QKVL, D_, D_);
    transp_k<<<dim3(D_/32, D_/32, L_), 256, 0, stream>>>(Wv, DD, Wqkv_t + 2 * DD, QKVL, D_, D_);
    transp_k<<<dim3(D_/32, D_/32, L_), 256, 0, stream>>>(Wo, DD, Wo_t,            DD,   D_, D_);
    transp_k<<<dim3(F_/32, D_/32, L_), 256, 0, stream>>>(W1, DF, W1_t,            DF,   F_, D_);
    transp_k<<<dim3(D_/32, F_/32, L_), 256, 0, stream>>>(W2, DF, W2_t,            DF,   D_, F_);
    bcat_k<<<L_, 256, 0, stream>>>(bq, bk, bv, bqkv);
    if (ws_ok)
        transp_k<<<dim3(V_/32, D_/32, 1), 256, 0, stream>>>(Wf, 0, Wf_t, 0, V_, D_);

    embed_k<<<BS_, 256, 0, stream>>>(x, tok, pos, h, h_bf);

    const dim3 gQKV(NQKV_/128, BS_/128);   // (18, 16)
    const dim3 gFF1(F_/128,    BS_/128);   // (24, 16)
    const dim3 gOUT(D_/128,    BS_/64);    // (6, 32)
    const dim3 gA(S_/32, B_*H_);           // (32, 24)
    const dim3 gV(S_/32, B_*H_);           // (32, 24)
    for (int i = 0; i < L_; ++i) {
        mgemm_k<128,128,0,false,true,false><<<gQKV, 256, 0, stream>>>(
            h_bf, Wqkv_t + (size_t)i * QKVL, bqkv + (size_t)i * NQKV_, nullptr, qkv_bf, BS_, NQKV_, D_);
        vtr_k<<<gV, 256, 0, stream>>>(qkv_bf, vT);
        fattn_k<<<gA, 128, 0, stream>>>(qkv_bf, vT, att_bf);
        mgemm_k<64,128,0,true,false,false><<<gOUT, 256, 0, stream>>>(
            att_bf, Wo_t + (size_t)i * DD, bo + (size_t)i * D_, tmp, nullptr, BS_, D_, D_);
        addln_k<<<BS_, 256, 0, stream>>>(tmp, h, ln1g + (size_t)i * D_, ln1b + (size_t)i * D_, h1, h1_bf);
        mgemm_k<128,128,1,false,true,false><<<gFF1, 256, 0, stream>>>(
            h1_bf, W1_t + (size_t)i * DF, b1 + (size_t)i * F_, nullptr, ff_bf, BS_, F_, D_);
        mgemm_k<64,128,0,true,false,false><<<gOUT, 256, 0, stream>>>(
            ff_bf, W2_t + (size_t)i * DF, b2 + (size_t)i * D_, tmp, nullptr, BS_, D_, F_);
        addln_k<<<BS_, 256, 0, stream>>>(tmp, h1, ln2g + (size_t)i * D_, ln2b + (size_t)i * D_, h, h_bf);
    }

    if (ws_ok) {
        cvt_k<<<(int)(HS / 1024), 256, 0, stream>>>(h, hbf_ws, (int)HS);
        // SW grid: M-tiles on x (16), N-panels on y (250) -> Wf_t fetched ~once.
        mgemm_k<128,128,0,true,false,true><<<dim3(BS_/128, V_/128), 256, 0, stream>>>(
            hbf_ws, Wf_t, bff, out, nullptr, BS_, V_, D_);
    } else {
        gemm_k<<<dim3(V_/64, BS_/64), 256, 0, stream>>>(h, Wf, bff, out, BS_, V_, D_);
    }
    lsm_k<<<BS_, 256, 0, stream>>>(out);
}

// Round 7
// 1462.849 us; speedup vs baseline: 10.4981x; 1.0013x over previous
//
#include <hip/hip_runtime.h>
#include <hip/hip_bf16.h>
#include <math.h>

#define B_ 2
#define S_ 1024
#define V_ 32000
#define D_ 768
#define F_ 3072
#define H_ 12
#define L_ 6
#define DH_ 64
#define BS_ (B_*S_)   // 2048
#define NQKV_ 2304
#define KVB_ 128

typedef __attribute__((ext_vector_type(8))) short short8;
typedef __attribute__((ext_vector_type(4))) float f32x4;

__device__ __forceinline__ unsigned short f2b(float f) {
    union { __hip_bfloat16 h; unsigned short u; } cv;
    cv.h = __float2bfloat16(f);
    return cv.u;
}

__device__ __forceinline__ void store_bf4(__hip_bfloat16* p, float a, float b, float c, float d) {
    unsigned long long pk = (unsigned long long)f2b(a)
        | ((unsigned long long)f2b(b) << 16)
        | ((unsigned long long)f2b(c) << 32)
        | ((unsigned long long)f2b(d) << 48);
    *(unsigned long long*)p = pk;
}

__device__ __forceinline__ void gld16(const void* g, void* l) {
    __builtin_amdgcn_global_load_lds(
        (const __attribute__((address_space(1))) unsigned int*)g,
        (__attribute__((address_space(3))) unsigned int*)l,
        16, 0, 0);
}

// ---------------- embedding (dual write f32 + bf16) ----------------
__global__ void embed_k(const int* __restrict__ x, const float* __restrict__ tok,
                        const float* __restrict__ pos, float* __restrict__ h,
                        __hip_bfloat16* __restrict__ hbf) {
    int bs = blockIdx.x;
    int s = bs % S_;
    int t = x[bs];
    for (int d = threadIdx.x; d < D_; d += blockDim.x) {
        float v = tok[(size_t)t * D_ + d] + pos[(size_t)s * D_ + d];
        h[(size_t)bs * D_ + d] = v;
        hbf[(size_t)bs * D_ + d] = __float2bfloat16(v);
    }
}

// ---------------- transpose+convert: src f32 [K][N] -> dst bf16 [N][K] ----------------
__global__ __launch_bounds__(256) void transp_k(const float* __restrict__ src, size_t sl,
                                                __hip_bfloat16* __restrict__ dst, size_t dl,
                                                int N, int K) {
    const float* S = src + (size_t)blockIdx.z * sl;
    __hip_bfloat16* Dp = dst + (size_t)blockIdx.z * dl;
    __shared__ float T[32][33];
    const int k0 = blockIdx.y * 32, n0 = blockIdx.x * 32;
    const int tid = threadIdx.x;
    const int r = tid >> 3, c4 = (tid & 7) * 4;
    float4 vv = *(const float4*)&S[(size_t)(k0 + r) * N + n0 + c4];
    T[r][c4 + 0] = vv.x; T[r][c4 + 1] = vv.y; T[r][c4 + 2] = vv.z; T[r][c4 + 3] = vv.w;
    __syncthreads();
    store_bf4(&Dp[(size_t)(n0 + r) * K + k0 + c4],
              T[c4 + 0][r], T[c4 + 1][r], T[c4 + 2][r], T[c4 + 3][r]);
}

// ---------------- concat qkv biases ----------------
__global__ void bcat_k(const float* __restrict__ bq, const float* __restrict__ bk,
                       const float* __restrict__ bv, float* __restrict__ dst) {
    int l = blockIdx.x;
    for (int j = threadIdx.x; j < D_; j += blockDim.x) {
        dst[(size_t)l * NQKV_ + j]          = bq[(size_t)l * D_ + j];
        dst[(size_t)l * NQKV_ + D_ + j]     = bk[(size_t)l * D_ + j];
        dst[(size_t)l * NQKV_ + 2 * D_ + j] = bv[(size_t)l * D_ + j];
    }
}

// ---------------- f32 -> bf16 vector convert ----------------
__global__ void cvt_k(const float* __restrict__ in, __hip_bfloat16* __restrict__ out, int n) {
    int i = (blockIdx.x * 256 + threadIdx.x) * 4;
    if (i < n) {
        float4 v = *(const float4*)&in[i];
        store_bf4(&out[i], v.x, v.y, v.z, v.w);
    }
}

// ---------------- V transpose: qkv[BS][2304] v-cols -> vT[bh][d][s] ----------------
__global__ __launch_bounds__(256) void vtr_k(const __hip_bfloat16* __restrict__ qkv,
                                             __hip_bfloat16* __restrict__ vT) {
    const int s0 = blockIdx.x * 32;
    const int bh = blockIdx.y;
    const int b = bh / H_, hh = bh % H_;
    const size_t rb = (size_t)b * S_;
    const int tid = threadIdx.x;
    const int sc = tid & 3, d = tid >> 2;
    const short* src = (const short*)qkv + (rb + s0 + sc * 8) * (size_t)NQKV_ + 2 * D_ + hh * DH_ + d;
    short8 pk;
    #pragma unroll
    for (int i = 0; i < 8; ++i) pk[i] = src[(size_t)i * NQKV_];
    *(short8*)&vT[((size_t)bh * DH_ + d) * S_ + s0 + sc * 8] = pk;
}

// ---------------- MFMA bf16 GEMM: C = act(A[M,K] @ Bt[N,K]^T + bias) ----------------
// SW: M on blockIdx.x (weight-panel grouping). XS: XCD-bijective swizzle so all
// M-blocks of one weight panel land on ONE XCD's L2 (requires nwg % 8 == 0).
template<int BM, int BN, int ACT, bool WF32, bool WBF, bool SW, bool XS>
__global__ __launch_bounds__(256) void mgemm_k(const __hip_bfloat16* __restrict__ A,
                                               const __hip_bfloat16* __restrict__ Bt,
                                               const float* __restrict__ bias,
                                               float* __restrict__ Cf,
                                               __hip_bfloat16* __restrict__ Cb,
                                               int M, int N, int K) {
    constexpr int WM = BM / 2, WN = BN / 2;
    constexpr int FM = WM / 16, FN = WN / 16;
    __shared__ __hip_bfloat16 Al[BM * 64];
    __shared__ __hip_bfloat16 Bl[BN * 64];
    const int tid = threadIdx.x;
    const int wid = tid >> 6, lane = tid & 63;
    const int wr = wid >> 1, wc = wid & 1;
    const int lrow = lane & 15, kq = lane >> 4;

    int bx = blockIdx.x, by = blockIdx.y;
    if (XS) {
        const int gx = gridDim.x;
        const int nwg = gx * gridDim.y;
        const int lin = by * gx + bx;
        const int logical = (lin & 7) * (nwg >> 3) + (lin >> 3);
        bx = logical % gx;
        by = logical / gx;
    }
    const int row0 = (SW ? bx : by) * BM;
    const int col0 = (SW ? by : bx) * BN;

    f32x4 acc[FM][FN];
    #pragma unroll
    for (int i = 0; i < FM; ++i)
        #pragma unroll
        for (int j = 0; j < FN; ++j)
            acc[i][j] = (f32x4){0.f, 0.f, 0.f, 0.f};

    const int srow = (lane >> 3);
    const int scol = (lane & 7) * 8;

    for (int kk = 0; kk < K; kk += 64) {
        #pragma unroll
        for (int i = 0; i < BM / 32; ++i)
            gld16(A + (size_t)(row0 + i * 32 + wid * 8 + srow) * K + kk + scol,
                  &Al[(i * 32 + wid * 8) * 64]);
        #pragma unroll
        for (int i = 0; i < BN / 32; ++i)
            gld16(Bt + (size_t)(col0 + i * 32 + wid * 8 + srow) * K + kk + scol,
                  &Bl[(i * 32 + wid * 8) * 64]);
        __syncthreads();

        #pragma unroll
        for (int kc = 0; kc < 2; ++kc) {
            short8 af[FM], bfr[FN];
            #pragma unroll
            for (int i = 0; i < FM; ++i)
                af[i] = *(const short8*)&Al[(wr * WM + i * 16 + lrow) * 64 + kc * 32 + kq * 8];
            #pragma unroll
            for (int j = 0; j < FN; ++j)
                bfr[j] = *(const short8*)&Bl[(wc * WN + j * 16 + lrow) * 64 + kc * 32 + kq * 8];
            #pragma unroll
            for (int i = 0; i < FM; ++i)
                #pragma unroll
                for (int j = 0; j < FN; ++j)
                    acc[i][j] = __builtin_amdgcn_mfma_f32_16x16x32_bf16(af[i], bfr[j], acc[i][j], 0, 0, 0);
        }
        __syncthreads();
    }

    #pragma unroll
    for (int i = 0; i < FM; ++i)
        #pragma unroll
        for (int j = 0; j < FN; ++j) {
            const int col = col0 + wc * WN + j * 16 + lrow;
            const float bv = bias[col];
            #pragma unroll
            for (int r = 0; r < 4; ++r) {
                const int row = row0 + wr * WM + i * 16 + kq * 4 + r;
                float vv = acc[i][j][r] + bv;
                if (ACT == 1) vv = 0.5f * vv * (1.0f + erff(vv * 0.70710678118654752f));
                if (WF32) Cf[(size_t)row * N + col] = vv;
                if (WBF)  Cb[(size_t)row * N + col] = __float2bfloat16(vv);
            }
        }
}

// ---------------- legacy f32 GEMM (fallback for logits if no workspace) ----------------
__global__ __launch_bounds__(256) void gemm_k(const float* __restrict__ A,
                                              const float* __restrict__ W,
                                              const float* __restrict__ bias,
                                              float* __restrict__ Cout,
                                              int M, int N, int K) {
    __shared__ float As[64][16];
    __shared__ float Bs[16][64];
    const int tid = threadIdx.x;
    const int tx = tid & 15, ty = tid >> 4;
    const int row0 = blockIdx.y * 64, col0 = blockIdx.x * 64;
    float acc[4][4] = {};

    for (int kk = 0; kk < K; kk += 16) {
        #pragma unroll
        for (int it = 0; it < 4; ++it) {
            int idx = tid + it * 256;
            int m = idx >> 4, k = idx & 15;
            As[m][k] = A[(size_t)(row0 + m) * K + kk + k];
            int r = idx >> 6, c = idx & 63;
            Bs[r][c] = W[(size_t)(kk + r) * N + col0 + c];
        }
        __syncthreads();
        #pragma unroll
        for (int k = 0; k < 16; ++k) {
            float a[4], b[4];
            #pragma unroll
            for (int i = 0; i < 4; ++i) a[i] = As[ty * 4 + i][k];
            #pragma unroll
            for (int j = 0; j < 4; ++j) b[j] = Bs[k][tx * 4 + j];
            #pragma unroll
            for (int i = 0; i < 4; ++i)
                #pragma unroll
                for (int j = 0; j < 4; ++j)
                    acc[i][j] += a[i] * b[j];
        }
        __syncthreads();
    }

    #pragma unroll
    for (int i = 0; i < 4; ++i) {
        int r = row0 + ty * 4 + i;
        #pragma unroll
        for (int j = 0; j < 4; ++j) {
            int c = col0 + tx * 4 + j;
            Cout[(size_t)r * N + c] = acc[i][j] + bias[c];
        }
    }
}

// ---------------- MFMA flash attention ----------------
// 256 thr = 4 waves, 64 q-rows/block (16/wave); KV tile 128. K/V staged via
// global_load_lds with pre-swizzled SOURCE (linear LDS dest). Staging cost per
// FLOP halved vs 2-wave version; 48 KB LDS -> 3 blocks/CU = 12 waves/CU.
__global__ __launch_bounds__(256) void fattn_k(const __hip_bfloat16* __restrict__ qkv,
                                               const __hip_bfloat16* __restrict__ vT,
                                               __hip_bfloat16* __restrict__ o) {
    const int qt0 = blockIdx.x * 64;
    const int bh = blockIdx.y;
    const int b = bh / H_, hh = bh % H_;
    const size_t rb = (size_t)b * S_;
    const int hoff = hh * DH_;

    __shared__ __hip_bfloat16 Ks[KVB_ * 64];    // 16 KB
    __shared__ __hip_bfloat16 Vt[64 * KVB_];    // 16 KB
    __shared__ __hip_bfloat16 Ps[64 * KVB_];    // 16 KB

    const int tid = threadIdx.x;
    const int w = tid >> 6, lane = tid & 63;
    const int lr = lane & 15, lk = lane >> 4;

    short8 aq[2];
    {
        const int qrow = qt0 + w * 16 + lr;
        #pragma unroll
        for (int kc = 0; kc < 2; ++kc)
            aq[kc] = *(const short8*)&qkv[(rb + qrow) * NQKV_ + hoff + kc * 32 + lk * 8];
    }

    f32x4 oacc[4];
    float m_i[4], l_i[4];
    #pragma unroll
    for (int r = 0; r < 4; ++r) {
        oacc[r] = (f32x4){0.f, 0.f, 0.f, 0.f};
        m_i[r] = -1e30f;
        l_i[r] = 0.f;
    }

    const size_t vbase = (size_t)bh * DH_ * S_;

    for (int kt0 = 0; kt0 < S_; kt0 += KVB_) {
        __syncthreads();                               // prev tile fully consumed
        // ---- stage K [128 k][64 d]: 4 x gld16 per wave ----
        #pragma unroll
        for (int t = 0; t < 4; ++t) {
            const int r0 = w * 32 + t * 8;
            const int r = r0 + (lane >> 3);
            const int cs = (lane & 7) ^ ((r & 7) ^ ((r >> 3) & 7));
            gld16(&qkv[(rb + kt0 + r) * NQKV_ + D_ + hoff + cs * 8], &Ks[r0 * 64]);
        }
        // ---- stage V^T [64 d][128 k]: 4 x gld16 per wave ----
        #pragma unroll
        for (int t = 0; t < 4; ++t) {
            const int d0 = w * 16 + t * 4;
            const int d = d0 + (lane >> 4);
            const int cs = (lane & 15) ^ (d & 15);
            gld16(&vT[vbase + (size_t)d * S_ + kt0 + cs * 8], &Vt[d0 * 128]);
        }
        __syncthreads();                               // tiles ready (drains vmcnt)

        // ---- scores S = Q @ K^T ----
        f32x4 s[8];
        #pragma unroll
        for (int j = 0; j < 8; ++j) s[j] = (f32x4){0.f, 0.f, 0.f, 0.f};
        __builtin_amdgcn_s_setprio(1);
        #pragma unroll
        for (int kc = 0; kc < 2; ++kc) {
            #pragma unroll
            for (int j = 0; j < 8; ++j) {
                int kr = j * 16 + lr;
                short8 bk = *(const short8*)((const char*)Ks + kr * 128
                              + ((kc * 64 + lk * 16) ^ ((((kr & 7) ^ ((kr >> 3) & 7)) << 4))));
                s[j] = __builtin_amdgcn_mfma_f32_16x16x32_bf16(aq[kc], bk, s[j], 0, 0, 0);
            }
        }
        __builtin_amdgcn_s_setprio(0);
        #pragma unroll
        for (int j = 0; j < 8; ++j)
            #pragma unroll
            for (int r = 0; r < 4; ++r)
                s[j][r] *= 0.03608439182435161f;       // 1/sqrt(768)

        // ---- online softmax (rows = w*16 + lk*4 + r; cols across lr-group) ----
        #pragma unroll
        for (int r = 0; r < 4; ++r) {
            float tmax = s[0][r];
            #pragma unroll
            for (int j = 1; j < 8; ++j) tmax = fmaxf(tmax, s[j][r]);
            #pragma unroll
            for (int off = 1; off <= 8; off <<= 1)
                tmax = fmaxf(tmax, __shfl_xor(tmax, off));
            float mnew = fmaxf(m_i[r], tmax);
            float corr = __expf(m_i[r] - mnew);
            m_i[r] = mnew;
            float psum = 0.f;
            const int prow = w * 16 + lk * 4 + r;
            #pragma unroll
            for (int j = 0; j < 8; ++j) {
                float p = __expf(s[j][r] - mnew);
                psum += p;
                *(__hip_bfloat16*)((char*)Ps + prow * 256
                    + (((j * 16 + lr) * 2) ^ ((prow & 15) << 4))) = __float2bfloat16(p);
            }
            #pragma unroll
            for (int off = 1; off <= 8; off <<= 1)
                psum += __shfl_xor(psum, off);
            l_i[r] = l_i[r] * corr + psum;
            #pragma unroll
            for (int jd = 0; jd < 4; ++jd) oacc[jd][r] *= corr;
        }

        // ---- PV: O += P @ V (wave-private Ps rows) ----
        __builtin_amdgcn_s_setprio(1);
        #pragma unroll
        for (int ks = 0; ks < 4; ++ks) {
            const int prow = w * 16 + lr;
            short8 pa = *(const short8*)((const char*)Ps + prow * 256
                          + ((ks * 64 + lk * 16) ^ ((prow & 15) << 4)));
            #pragma unroll
            for (int jd = 0; jd < 4; ++jd) {
                int vr = jd * 16 + lr;
                short8 vb = *(const short8*)((const char*)Vt + vr * 256
                              + ((ks * 64 + lk * 16) ^ ((vr & 15) << 4)));
                oacc[jd] = __builtin_amdgcn_mfma_f32_16x16x32_bf16(pa, vb, oacc[jd], 0, 0, 0);
            }
        }
        __builtin_amdgcn_s_setprio(0);
    }

    #pragma unroll
    for (int r = 0; r < 4; ++r) {
        float inv = 1.0f / l_i[r];
        const int row = qt0 + w * 16 + lk * 4 + r;
        #pragma unroll
        for (int jd = 0; jd < 4; ++jd)
            o[(rb + row) * (size_t)D_ + hoff + jd * 16 + lr] = __float2bfloat16(oacc[jd][r] * inv);
    }
}

// ---------------- add + layernorm; dual write f32 + bf16 ----------------
__global__ __launch_bounds__(256) void addln_k(const float* __restrict__ a,
                                               const float* __restrict__ b,
                                               const float* __restrict__ g,
                                               const float* __restrict__ beta,
                                               float* __restrict__ out,
                                               __hip_bfloat16* __restrict__ out_bf) {
    const int r = blockIdx.x;
    const int tid = threadIdx.x;
    __shared__ float red[256];
    float xv[3];
    float s = 0.f;
    #pragma unroll
    for (int i = 0; i < 3; ++i) {
        int d = tid + i * 256;
        xv[i] = a[(size_t)r * D_ + d] + b[(size_t)r * D_ + d];
        s += xv[i];
    }
    red[tid] = s; __syncthreads();
    for (int st = 128; st > 0; st >>= 1) { if (tid < st) red[tid] += red[tid + st]; __syncthreads(); }
    float mu = red[0] * (1.0f / D_);
    __syncthreads();
    s = 0.f;
    #pragma unroll
    for (int i = 0; i < 3; ++i) { float dd = xv[i] - mu; s += dd * dd; }
    red[tid] = s; __syncthreads();
    for (int st = 128; st > 0; st >>= 1) { if (tid < st) red[tid] += red[tid + st]; __syncthreads(); }
    float rstd = rsqrtf(red[0] * (1.0f / D_) + 1e-5f);
    #pragma unroll
    for (int i = 0; i < 3; ++i) {
        int d = tid + i * 256;
        float v = (xv[i] - mu) * rstd * g[d] + beta[d];
        out[(size_t)r * D_ + d] = v;
        out_bf[(size_t)r * D_ + d] = __float2bfloat16(v);
    }
}

// ---------------- in-place log-softmax over f32 logits rows (float4) ----------------
__global__ __launch_bounds__(256) void lsm_k(float* __restrict__ lp) {
    const int r = blockIdx.x;
    const int tid = threadIdx.x;
    __shared__ float red[256];
    float* row = lp + (size_t)r * V_;
    float m = -1e30f;
    for (int i = tid * 4; i < V_; i += 1024) {
        float4 v = *(const float4*)&row[i];
        m = fmaxf(m, fmaxf(fmaxf(v.x, v.y), fmaxf(v.z, v.w)));
    }
    red[tid] = m; __syncthreads();
    for (int st = 128; st > 0; st >>= 1) { if (tid < st) red[tid] = fmaxf(red[tid], red[tid + st]); __syncthreads(); }
    m = red[0]; __syncthreads();
    float l = 0.f;
    for (int i = tid * 4; i < V_; i += 1024) {
        float4 v = *(const float4*)&row[i];
        l += __expf(v.x - m) + __expf(v.y - m) + __expf(v.z - m) + __expf(v.w - m);
    }
    red[tid] = l; __syncthreads();
    for (int st = 128; st > 0; st >>= 1) { if (tid < st) red[tid] += red[tid + st]; __syncthreads(); }
    float sub = m + __logf(red[0]);
    for (int i = tid * 4; i < V_; i += 1024) {
        float4 v = *(const float4*)&row[i];
        v.x -= sub; v.y -= sub; v.z -= sub; v.w -= sub;
        *(float4*)&row[i] = v;
    }
}

extern "C" void kernel_launch(void* const* d_in, const int* in_sizes, int n_in,
                              void* d_out, int out_size, void* d_ws, size_t ws_size,
                              hipStream_t stream) {
    const int*   x    = (const int*)  d_in[0];
    const float* tok  = (const float*)d_in[1];
    const float* pos  = (const float*)d_in[2];
    const float* Wq   = (const float*)d_in[3];
    const float* bq   = (const float*)d_in[4];
    const float* Wk   = (const float*)d_in[5];
    const float* bk   = (const float*)d_in[6];
    const float* Wv   = (const float*)d_in[7];
    const float* bv   = (const float*)d_in[8];
    const float* Wo   = (const float*)d_in[9];
    const float* bo   = (const float*)d_in[10];
    const float* ln1g = (const float*)d_in[11];
    const float* ln1b = (const float*)d_in[12];
    const float* W1   = (const float*)d_in[13];
    const float* b1   = (const float*)d_in[14];
    const float* W2   = (const float*)d_in[15];
    const float* b2   = (const float*)d_in[16];
    const float* ln2g = (const float*)d_in[17];
    const float* ln2b = (const float*)d_in[18];
    const float* Wf   = (const float*)d_in[19];
    const float* bff  = (const float*)d_in[20];

    float* out = (float*)d_out;
    const size_t HS = (size_t)BS_ * D_;              // 1,572,864

    // f32-slot layout inside logits scratch region [0, BS_*V_):
    __hip_bfloat16* qkv_bf = (__hip_bfloat16*)out;               // BS*2304 bf16
    __hip_bfloat16* vT     = (__hip_bfloat16*)(out + 2359296);   // BS*768 bf16
    __hip_bfloat16* att_bf = (__hip_bfloat16*)(out + 4718592);
    float* tmp   = out + 5505024;
    float* h1    = out + 7077888;
    __hip_bfloat16* h1_bf  = (__hip_bfloat16*)(out + 8650752);
    __hip_bfloat16* ff_bf  = (__hip_bfloat16*)(out + 9437184);
    __hip_bfloat16* h_bf   = (__hip_bfloat16*)(out + 12582912);
    __hip_bfloat16* Wqkv_t = (__hip_bfloat16*)(out + 13369344);  // 6 x [2304][768]
    __hip_bfloat16* Wo_t   = (__hip_bfloat16*)(out + 18677760);  // 6 x [768][768]
    __hip_bfloat16* W1_t   = (__hip_bfloat16*)(out + 20447232);  // 6 x [3072][768]
    __hip_bfloat16* W2_t   = (__hip_bfloat16*)(out + 27525120);  // 6 x [768][3072]
    float* bqkv  = out + 34603008;                   // 6 x 2304
    float* h     = out + (size_t)BS_ * V_;           // tail: hset output

    const bool ws_ok = ws_size >= (size_t)(24576000ULL * 2 + HS * 2);
    __hip_bfloat16* Wf_t   = (__hip_bfloat16*)d_ws;              // [32000][768]
    __hip_bfloat16* hbf_ws = (__hip_bfloat16*)((char*)d_ws + 49152000);

    // ---- weight transpose/convert pre-pass ----
    const size_t DD = (size_t)D_ * D_, DF = (size_t)D_ * F_;
    const size_t QKVL = (size_t)NQKV_ * D_;
    transp_k<<<dim3(D_/32, D_/32, L_), 256, 0, stream>>>(Wq, DD, Wqkv_t,          QKVL, D_, D_);
    transp_k<<<dim3(D_/32, D_/32, L_), 256, 0, stream>>>(Wk, DD, Wqkv_t + DD,     QKVL, D_, D_);
    transp_k<<<dim3(D_/32, D_/32, L_), 256, 0, stream>>>(Wv, DD, Wqkv_t + 2 * DD, QKVL, D_, D_);
    transp_k<<<dim3(D_/32, D_/32, L_), 256, 0, stream>>>(Wo, DD, Wo_t,            DD,   D_, D_);
    transp_k<<<dim3(F_/32, D_/32, L_), 256, 0, stream>>>(W1, DF, W1_t,            DF,   F_, D_);
    transp_k<<<dim3(D_/32, F_/32, L_), 256, 0, stream>>>(W2, DF, W2_t,            DF,   D_, F_);
    bcat_k<<<L_, 256, 0, stream>>>(bq, bk, bv, bqkv);
    if (ws_ok)
        transp_k<<<dim3(V_/32, D_/32, 1), 256, 0, stream>>>(Wf, 0, Wf_t, 0, V_, D_);

    embed_k<<<BS_, 256, 0, stream>>>(x, tok, pos, h, h_bf);

    const dim3 gQKV(NQKV_/128, BS_/128);   // (18, 16)
    const dim3 gFF1(F_/128,    BS_/128);   // (24, 16)
    const dim3 gOUT(D_/128,    BS_/64);    // (6, 32)
    const dim3 gA(S_/64, B_*H_);           // (16, 24)
    const dim3 gV(S_/32, B_*H_);           // (32, 24)
    for (int i = 0; i < L_; ++i) {
        mgemm_k<128,128,0,false,true,false,false><<<gQKV, 256, 0, stream>>>(
            h_bf, Wqkv_t + (size_t)i * QKVL, bqkv + (size_t)i * NQKV_, nullptr, qkv_bf, BS_, NQKV_, D_);
        vtr_k<<<gV, 256, 0, stream>>>(qkv_bf, vT);
        fattn_k<<<gA, 256, 0, stream>>>(qkv_bf, vT, att_bf);
        mgemm_k<64,128,0,true,false,false,false><<<gOUT, 256, 0, stream>>>(
            att_bf, Wo_t + (size_t)i * DD, bo + (size_t)i * D_, tmp, nullptr, BS_, D_, D_);
        addln_k<<<BS_, 256, 0, stream>>>(tmp, h, ln1g + (size_t)i * D_, ln1b + (size_t)i * D_, h1, h1_bf);
        mgemm_k<128,128,1,false,true,false,false><<<gFF1, 256, 0, stream>>>(
            h1_bf, W1_t + (size_t)i * DF, b1 + (size_t)i * F_, nullptr, ff_bf, BS_, F_, D_);
        mgemm_k<64,128,0,true,false,false,false><<<gOUT, 256, 0, stream>>>(
            ff_bf, W2_t + (size_t)i * DF, b2 + (size_t)i * D_, tmp, nullptr, BS_, D_, F_);
        addln_k<<<BS_, 256, 0, stream>>>(tmp, h1, ln2g + (size_t)i * D_, ln2b + (size_t)i * D_, h, h_bf);
    }

    if (ws_ok) {
        cvt_k<<<(int)(HS / 1024), 256, 0, stream>>>(h, hbf_ws, (int)HS);
        // SW+XS: M fastest within a 16-block panel group; panel groups pinned per-XCD.
        mgemm_k<128,128,0,true,false,true,true><<<dim3(BS_/128, V_/128), 256, 0, stream>>>(
            hbf_ws, Wf_t, bff, out, nullptr, BS_, V_, D_);
    } else {
        gemm_k<<<dim3(V_/64, BS_/64), 256, 0, stream>>>(h, Wf, bff, out, BS_, V_, D_);
    }
    lsm_k<<<BS_, 256, 0, stream>>>(out);
}

// Round 8
// 1313.501 us; speedup vs baseline: 11.6918x; 1.1137x over previous
//
#include <hip/hip_runtime.h>
#include <hip/hip_bf16.h>
#include <math.h>

#define B_ 2
#define S_ 1024
#define V_ 32000
#define D_ 768
#define F_ 3072
#define H_ 12
#define L_ 6
#define DH_ 64
#define BS_ (B_*S_)   // 2048
#define NQKV_ 2304
#define KVB_ 128

typedef __attribute__((ext_vector_type(8))) short short8;
typedef __attribute__((ext_vector_type(4))) float f32x4;

__device__ __forceinline__ unsigned short f2b(float f) {
    union { __hip_bfloat16 h; unsigned short u; } cv;
    cv.h = __float2bfloat16(f);
    return cv.u;
}

__device__ __forceinline__ void store_bf4(__hip_bfloat16* p, float a, float b, float c, float d) {
    unsigned long long pk = (unsigned long long)f2b(a)
        | ((unsigned long long)f2b(b) << 16)
        | ((unsigned long long)f2b(c) << 32)
        | ((unsigned long long)f2b(d) << 48);
    *(unsigned long long*)p = pk;
}

__device__ __forceinline__ void gld16(const void* g, void* l) {
    __builtin_amdgcn_global_load_lds(
        (const __attribute__((address_space(1))) unsigned int*)g,
        (__attribute__((address_space(3))) unsigned int*)l,
        16, 0, 0);
}

// ---------------- embedding (dual write f32 + bf16) ----------------
__global__ void embed_k(const int* __restrict__ x, const float* __restrict__ tok,
                        const float* __restrict__ pos, float* __restrict__ h,
                        __hip_bfloat16* __restrict__ hbf) {
    int bs = blockIdx.x;
    int s = bs % S_;
    int t = x[bs];
    for (int d = threadIdx.x; d < D_; d += blockDim.x) {
        float v = tok[(size_t)t * D_ + d] + pos[(size_t)s * D_ + d];
        h[(size_t)bs * D_ + d] = v;
        hbf[(size_t)bs * D_ + d] = __float2bfloat16(v);
    }
}

// ---------------- transpose+convert: src f32 [K][N] -> dst bf16 [N][K] ----------------
__global__ __launch_bounds__(256) void transp_k(const float* __restrict__ src, size_t sl,
                                                __hip_bfloat16* __restrict__ dst, size_t dl,
                                                int N, int K) {
    const float* S = src + (size_t)blockIdx.z * sl;
    __hip_bfloat16* Dp = dst + (size_t)blockIdx.z * dl;
    __shared__ float T[32][33];
    const int k0 = blockIdx.y * 32, n0 = blockIdx.x * 32;
    const int tid = threadIdx.x;
    const int r = tid >> 3, c4 = (tid & 7) * 4;
    float4 vv = *(const float4*)&S[(size_t)(k0 + r) * N + n0 + c4];
    T[r][c4 + 0] = vv.x; T[r][c4 + 1] = vv.y; T[r][c4 + 2] = vv.z; T[r][c4 + 3] = vv.w;
    __syncthreads();
    store_bf4(&Dp[(size_t)(n0 + r) * K + k0 + c4],
              T[c4 + 0][r], T[c4 + 1][r], T[c4 + 2][r], T[c4 + 3][r]);
}

// ---------------- concat qkv biases ----------------
__global__ void bcat_k(const float* __restrict__ bq, const float* __restrict__ bk,
                       const float* __restrict__ bv, float* __restrict__ dst) {
    int l = blockIdx.x;
    for (int j = threadIdx.x; j < D_; j += blockDim.x) {
        dst[(size_t)l * NQKV_ + j]          = bq[(size_t)l * D_ + j];
        dst[(size_t)l * NQKV_ + D_ + j]     = bk[(size_t)l * D_ + j];
        dst[(size_t)l * NQKV_ + 2 * D_ + j] = bv[(size_t)l * D_ + j];
    }
}

// ---------------- f32 -> bf16 vector convert ----------------
__global__ void cvt_k(const float* __restrict__ in, __hip_bfloat16* __restrict__ out, int n) {
    int i = (blockIdx.x * 256 + threadIdx.x) * 4;
    if (i < n) {
        float4 v = *(const float4*)&in[i];
        store_bf4(&out[i], v.x, v.y, v.z, v.w);
    }
}

// ---------------- MFMA bf16 GEMM: C = act(A[M,K] @ Bt[N,K]^T + bias) ----------------
// LDS tiles are XOR-swizzled (T2): staged with pre-swizzled global source chunks
// (linear gld16 dest) and read with byte ^= (row&7)<<4 -> 16-way conflicts -> 2-way.
// SW: M on blockIdx.x. XS: XCD-bijective block swizzle. WVT: QKV mode, V-cols
// (>=1536) written directly to vT[bh][d][s] (fused V-transpose).
template<int BM, int BN, int ACT, bool WF32, bool WBF, bool SW, bool XS, bool WVT>
__global__ __launch_bounds__(256) void mgemm_k(const __hip_bfloat16* __restrict__ A,
                                               const __hip_bfloat16* __restrict__ Bt,
                                               const float* __restrict__ bias,
                                               float* __restrict__ Cf,
                                               __hip_bfloat16* __restrict__ Cb,
                                               __hip_bfloat16* __restrict__ vTp,
                                               int M, int N, int K) {
    constexpr int WM = BM / 2, WN = BN / 2;
    constexpr int FM = WM / 16, FN = WN / 16;
    __shared__ __hip_bfloat16 Al[BM * 64];
    __shared__ __hip_bfloat16 Bl[BN * 64];
    const int tid = threadIdx.x;
    const int wid = tid >> 6, lane = tid & 63;
    const int wr = wid >> 1, wc = wid & 1;
    const int lrow = lane & 15, kq = lane >> 4;

    int bx = blockIdx.x, by = blockIdx.y;
    if (XS) {
        const int gx = gridDim.x;
        const int nwg = gx * gridDim.y;
        const int lin = by * gx + bx;
        const int logical = (lin & 7) * (nwg >> 3) + (lin >> 3);
        bx = logical % gx;
        by = logical / gx;
    }
    const int row0 = (SW ? bx : by) * BM;
    const int col0 = (SW ? by : bx) * BN;

    f32x4 acc[FM][FN];
    #pragma unroll
    for (int i = 0; i < FM; ++i)
        #pragma unroll
        for (int j = 0; j < FN; ++j)
            acc[i][j] = (f32x4){0.f, 0.f, 0.f, 0.f};

    const int srow = (lane >> 3);
    const int scol = ((lane & 7) ^ srow) * 8;   // pre-swizzled source chunk (T21)

    for (int kk = 0; kk < K; kk += 64) {
        #pragma unroll
        for (int i = 0; i < BM / 32; ++i)
            gld16(A + (size_t)(row0 + i * 32 + wid * 8 + srow) * K + kk + scol,
                  &Al[(i * 32 + wid * 8) * 64]);
        #pragma unroll
        for (int i = 0; i < BN / 32; ++i)
            gld16(Bt + (size_t)(col0 + i * 32 + wid * 8 + srow) * K + kk + scol,
                  &Bl[(i * 32 + wid * 8) * 64]);
        __syncthreads();

        #pragma unroll
        for (int kc = 0; kc < 2; ++kc) {
            short8 af[FM], bfr[FN];
            #pragma unroll
            for (int i = 0; i < FM; ++i) {
                const int row = wr * WM + i * 16 + lrow;
                af[i] = *(const short8*)((const char*)Al + row * 128
                          + ((kc * 64 + kq * 16) ^ ((row & 7) << 4)));
            }
            #pragma unroll
            for (int j = 0; j < FN; ++j) {
                const int row = wc * WN + j * 16 + lrow;
                bfr[j] = *(const short8*)((const char*)Bl + row * 128
                          + ((kc * 64 + kq * 16) ^ ((row & 7) << 4)));
            }
            #pragma unroll
            for (int i = 0; i < FM; ++i)
                #pragma unroll
                for (int j = 0; j < FN; ++j)
                    acc[i][j] = __builtin_amdgcn_mfma_f32_16x16x32_bf16(af[i], bfr[j], acc[i][j], 0, 0, 0);
        }
        __syncthreads();
    }

    #pragma unroll
    for (int i = 0; i < FM; ++i)
        #pragma unroll
        for (int j = 0; j < FN; ++j) {
            const int col = col0 + wc * WN + j * 16 + lrow;
            const float bv = bias[col];
            const int rowq = row0 + wr * WM + i * 16 + kq * 4;
            if (WVT && col >= 1536) {
                // V columns: write straight into vT[bh][d][s]; acc quad = 4 consecutive s.
                const int cv = col - 1536;
                const int bh = (rowq >> 10) * H_ + (cv >> 6);
                store_bf4(&vTp[((size_t)bh * DH_ + (cv & 63)) * S_ + (rowq & 1023)],
                          acc[i][j][0] + bv, acc[i][j][1] + bv,
                          acc[i][j][2] + bv, acc[i][j][3] + bv);
            } else {
                #pragma unroll
                for (int r = 0; r < 4; ++r) {
                    const int row = rowq + r;
                    float vv = acc[i][j][r] + bv;
                    if (ACT == 1) vv = 0.5f * vv * (1.0f + erff(vv * 0.70710678118654752f));
                    if (WF32) Cf[(size_t)row * N + col] = vv;
                    if (WBF)  Cb[(size_t)row * N + col] = __float2bfloat16(vv);
                }
            }
        }
}

// ---------------- legacy f32 GEMM (fallback for logits if no workspace) ----------------
__global__ __launch_bounds__(256) void gemm_k(const float* __restrict__ A,
                                              const float* __restrict__ W,
                                              const float* __restrict__ bias,
                                              float* __restrict__ Cout,
                                              int M, int N, int K) {
    __shared__ float As[64][16];
    __shared__ float Bs[16][64];
    const int tid = threadIdx.x;
    const int tx = tid & 15, ty = tid >> 4;
    const int row0 = blockIdx.y * 64, col0 = blockIdx.x * 64;
    float acc[4][4] = {};

    for (int kk = 0; kk < K; kk += 16) {
        #pragma unroll
        for (int it = 0; it < 4; ++it) {
            int idx = tid + it * 256;
            int m = idx >> 4, k = idx & 15;
            As[m][k] = A[(size_t)(row0 + m) * K + kk + k];
            int r = idx >> 6, c = idx & 63;
            Bs[r][c] = W[(size_t)(kk + r) * N + col0 + c];
        }
        __syncthreads();
        #pragma unroll
        for (int k = 0; k < 16; ++k) {
            float a[4], b[4];
            #pragma unroll
            for (int i = 0; i < 4; ++i) a[i] = As[ty * 4 + i][k];
            #pragma unroll
            for (int j = 0; j < 4; ++j) b[j] = Bs[k][tx * 4 + j];
            #pragma unroll
            for (int i = 0; i < 4; ++i)
                #pragma unroll
                for (int j = 0; j < 4; ++j)
                    acc[i][j] += a[i] * b[j];
        }
        __syncthreads();
    }

    #pragma unroll
    for (int i = 0; i < 4; ++i) {
        int r = row0 + ty * 4 + i;
        #pragma unroll
        for (int j = 0; j < 4; ++j) {
            int c = col0 + tx * 4 + j;
            Cout[(size_t)r * N + c] = acc[i][j] + bias[c];
        }
    }
}

// ---------------- MFMA flash attention ----------------
// 256 thr = 4 waves, 64 q-rows/block (16/wave); KV tile 128. K/V staged via
// global_load_lds with pre-swizzled SOURCE (linear LDS dest).
__global__ __launch_bounds__(256) void fattn_k(const __hip_bfloat16* __restrict__ qkv,
                                               const __hip_bfloat16* __restrict__ vT,
                                               __hip_bfloat16* __restrict__ o) {
    const int qt0 = blockIdx.x * 64;
    const int bh = blockIdx.y;
    const int b = bh / H_, hh = bh % H_;
    const size_t rb = (size_t)b * S_;
    const int hoff = hh * DH_;

    __shared__ __hip_bfloat16 Ks[KVB_ * 64];    // 16 KB
    __shared__ __hip_bfloat16 Vt[64 * KVB_];    // 16 KB
    __shared__ __hip_bfloat16 Ps[64 * KVB_];    // 16 KB

    const int tid = threadIdx.x;
    const int w = tid >> 6, lane = tid & 63;
    const int lr = lane & 15, lk = lane >> 4;

    short8 aq[2];
    {
        const int qrow = qt0 + w * 16 + lr;
        #pragma unroll
        for (int kc = 0; kc < 2; ++kc)
            aq[kc] = *(const short8*)&qkv[(rb + qrow) * NQKV_ + hoff + kc * 32 + lk * 8];
    }

    f32x4 oacc[4];
    float m_i[4], l_i[4];
    #pragma unroll
    for (int r = 0; r < 4; ++r) {
        oacc[r] = (f32x4){0.f, 0.f, 0.f, 0.f};
        m_i[r] = -1e30f;
        l_i[r] = 0.f;
    }

    const size_t vbase = (size_t)bh * DH_ * S_;

    for (int kt0 = 0; kt0 < S_; kt0 += KVB_) {
        __syncthreads();                               // prev tile fully consumed
        // ---- stage K [128 k][64 d]: 4 x gld16 per wave ----
        #pragma unroll
        for (int t = 0; t < 4; ++t) {
            const int r0 = w * 32 + t * 8;
            const int r = r0 + (lane >> 3);
            const int cs = (lane & 7) ^ ((r & 7) ^ ((r >> 3) & 7));
            gld16(&qkv[(rb + kt0 + r) * NQKV_ + D_ + hoff + cs * 8], &Ks[r0 * 64]);
        }
        // ---- stage V^T [64 d][128 k]: 4 x gld16 per wave ----
        #pragma unroll
        for (int t = 0; t < 4; ++t) {
            const int d0 = w * 16 + t * 4;
            const int d = d0 + (lane >> 4);
            const int cs = (lane & 15) ^ (d & 15);
            gld16(&vT[vbase + (size_t)d * S_ + kt0 + cs * 8], &Vt[d0 * 128]);
        }
        __syncthreads();                               // tiles ready (drains vmcnt)

        // ---- scores S = Q @ K^T ----
        f32x4 s[8];
        #pragma unroll
        for (int j = 0; j < 8; ++j) s[j] = (f32x4){0.f, 0.f, 0.f, 0.f};
        __builtin_amdgcn_s_setprio(1);
        #pragma unroll
        for (int kc = 0; kc < 2; ++kc) {
            #pragma unroll
            for (int j = 0; j < 8; ++j) {
                int kr = j * 16 + lr;
                short8 bk = *(const short8*)((const char*)Ks + kr * 128
                              + ((kc * 64 + lk * 16) ^ ((((kr & 7) ^ ((kr >> 3) & 7)) << 4))));
                s[j] = __builtin_amdgcn_mfma_f32_16x16x32_bf16(aq[kc], bk, s[j], 0, 0, 0);
            }
        }
        __builtin_amdgcn_s_setprio(0);
        #pragma unroll
        for (int j = 0; j < 8; ++j)
            #pragma unroll
            for (int r = 0; r < 4; ++r)
                s[j][r] *= 0.03608439182435161f;       // 1/sqrt(768)

        // ---- online softmax ----
        #pragma unroll
        for (int r = 0; r < 4; ++r) {
            float tmax = s[0][r];
            #pragma unroll
            for (int j = 1; j < 8; ++j) tmax = fmaxf(tmax, s[j][r]);
            #pragma unroll
            for (int off = 1; off <= 8; off <<= 1)
                tmax = fmaxf(tmax, __shfl_xor(tmax, off));
            float mnew = fmaxf(m_i[r], tmax);
            float corr = __expf(m_i[r] - mnew);
            m_i[r] = mnew;
            float psum = 0.f;
            const int prow = w * 16 + lk * 4 + r;
            #pragma unroll
            for (int j = 0; j < 8; ++j) {
                float p = __expf(s[j][r] - mnew);
                psum += p;
                *(__hip_bfloat16*)((char*)Ps + prow * 256
                    + (((j * 16 + lr) * 2) ^ ((prow & 15) << 4))) = __float2bfloat16(p);
            }
            #pragma unroll
            for (int off = 1; off <= 8; off <<= 1)
                psum += __shfl_xor(psum, off);
            l_i[r] = l_i[r] * corr + psum;
            #pragma unroll
            for (int jd = 0; jd < 4; ++jd) oacc[jd][r] *= corr;
        }

        // ---- PV: O += P @ V ----
        __builtin_amdgcn_s_setprio(1);
        #pragma unroll
        for (int ks = 0; ks < 4; ++ks) {
            const int prow = w * 16 + lr;
            short8 pa = *(const short8*)((const char*)Ps + prow * 256
                          + ((ks * 64 + lk * 16) ^ ((prow & 15) << 4)));
            #pragma unroll
            for (int jd = 0; jd < 4; ++jd) {
                int vr = jd * 16 + lr;
                short8 vb = *(const short8*)((const char*)Vt + vr * 256
                              + ((ks * 64 + lk * 16) ^ ((vr & 15) << 4)));
                oacc[jd] = __builtin_amdgcn_mfma_f32_16x16x32_bf16(pa, vb, oacc[jd], 0, 0, 0);
            }
        }
        __builtin_amdgcn_s_setprio(0);
    }

    #pragma unroll
    for (int r = 0; r < 4; ++r) {
        float inv = 1.0f / l_i[r];
        const int row = qt0 + w * 16 + lk * 4 + r;
        #pragma unroll
        for (int jd = 0; jd < 4; ++jd)
            o[(rb + row) * (size_t)D_ + hoff + jd * 16 + lr] = __float2bfloat16(oacc[jd][r] * inv);
    }
}

// ---------------- add + layernorm; dual write f32 + bf16 ----------------
__global__ __launch_bounds__(256) void addln_k(const float* __restrict__ a,
                                               const float* __restrict__ b,
                                               const float* __restrict__ g,
                                               const float* __restrict__ beta,
                                               float* __restrict__ out,
                                               __hip_bfloat16* __restrict__ out_bf) {
    const int r = blockIdx.x;
    const int tid = threadIdx.x;
    __shared__ float red[256];
    float xv[3];
    float s = 0.f;
    #pragma unroll
    for (int i = 0; i < 3; ++i) {
        int d = tid + i * 256;
        xv[i] = a[(size_t)r * D_ + d] + b[(size_t)r * D_ + d];
        s += xv[i];
    }
    red[tid] = s; __syncthreads();
    for (int st = 128; st > 0; st >>= 1) { if (tid < st) red[tid] += red[tid + st]; __syncthreads(); }
    float mu = red[0] * (1.0f / D_);
    __syncthreads();
    s = 0.f;
    #pragma unroll
    for (int i = 0; i < 3; ++i) { float dd = xv[i] - mu; s += dd * dd; }
    red[tid] = s; __syncthreads();
    for (int st = 128; st > 0; st >>= 1) { if (tid < st) red[tid] += red[tid + st]; __syncthreads(); }
    float rstd = rsqrtf(red[0] * (1.0f / D_) + 1e-5f);
    #pragma unroll
    for (int i = 0; i < 3; ++i) {
        int d = tid + i * 256;
        float v = (xv[i] - mu) * rstd * g[d] + beta[d];
        out[(size_t)r * D_ + d] = v;
        out_bf[(size_t)r * D_ + d] = __float2bfloat16(v);
    }
}

// ---------------- in-place log-softmax, online (m,l) single-read + subtract pass ----------------
__global__ __launch_bounds__(256) void lsm_k(float* __restrict__ lp) {
    const int r = blockIdx.x;
    const int tid = threadIdx.x;
    __shared__ float rm[256], rl[256];
    float* row = lp + (size_t)r * V_;
    float mt = -1e30f, lt = 0.f;
    for (int i = tid * 4; i < V_; i += 1024) {
        float4 v = *(const float4*)&row[i];
        float c = fmaxf(fmaxf(v.x, v.y), fmaxf(v.z, v.w));
        if (c > mt) { lt *= __expf(mt - c); mt = c; }
        lt += __expf(v.x - mt) + __expf(v.y - mt) + __expf(v.z - mt) + __expf(v.w - mt);
    }
    rm[tid] = mt; rl[tid] = lt; __syncthreads();
    for (int st = 128; st > 0; st >>= 1) {
        if (tid < st) {
            float m2 = rm[tid + st], l2 = rl[tid + st];
            float M = fmaxf(rm[tid], m2);
            rl[tid] = rl[tid] * __expf(rm[tid] - M) + l2 * __expf(m2 - M);
            rm[tid] = M;
        }
        __syncthreads();
    }
    float sub = rm[0] + __logf(rl[0]);
    for (int i = tid * 4; i < V_; i += 1024) {
        float4 v = *(const float4*)&row[i];
        v.x -= sub; v.y -= sub; v.z -= sub; v.w -= sub;
        *(float4*)&row[i] = v;
    }
}

extern "C" void kernel_launch(void* const* d_in, const int* in_sizes, int n_in,
                              void* d_out, int out_size, void* d_ws, size_t ws_size,
                              hipStream_t stream) {
    const int*   x    = (const int*)  d_in[0];
    const float* tok  = (const float*)d_in[1];
    const float* pos  = (const float*)d_in[2];
    const float* Wq   = (const float*)d_in[3];
    const float* bq   = (const float*)d_in[4];
    const float* Wk   = (const float*)d_in[5];
    const float* bk   = (const float*)d_in[6];
    const float* Wv   = (const float*)d_in[7];
    const float* bv   = (const float*)d_in[8];
    const float* Wo   = (const float*)d_in[9];
    const float* bo   = (const float*)d_in[10];
    const float* ln1g = (const float*)d_in[11];
    const float* ln1b = (const float*)d_in[12];
    const float* W1   = (const float*)d_in[13];
    const float* b1   = (const float*)d_in[14];
    const float* W2   = (const float*)d_in[15];
    const float* b2   = (const float*)d_in[16];
    const float* ln2g = (const float*)d_in[17];
    const float* ln2b = (const float*)d_in[18];
    const float* Wf   = (const float*)d_in[19];
    const float* bff  = (const float*)d_in[20];

    float* out = (float*)d_out;
    const size_t HS = (size_t)BS_ * D_;              // 1,572,864

    // f32-slot layout inside logits scratch region [0, BS_*V_):
    __hip_bfloat16* qkv_bf = (__hip_bfloat16*)out;               // BS*2304 bf16
    __hip_bfloat16* vT     = (__hip_bfloat16*)(out + 2359296);   // BS*768 bf16
    __hip_bfloat16* att_bf = (__hip_bfloat16*)(out + 4718592);
    float* tmp   = out + 5505024;
    float* h1    = out + 7077888;
    __hip_bfloat16* h1_bf  = (__hip_bfloat16*)(out + 8650752);
    __hip_bfloat16* ff_bf  = (__hip_bfloat16*)(out + 9437184);
    __hip_bfloat16* h_bf   = (__hip_bfloat16*)(out + 12582912);
    __hip_bfloat16* Wqkv_t = (__hip_bfloat16*)(out + 13369344);  // 6 x [2304][768]
    __hip_bfloat16* Wo_t   = (__hip_bfloat16*)(out + 18677760);  // 6 x [768][768]
    __hip_bfloat16* W1_t   = (__hip_bfloat16*)(out + 20447232);  // 6 x [3072][768]
    __hip_bfloat16* W2_t   = (__hip_bfloat16*)(out + 27525120);  // 6 x [768][3072]
    float* bqkv  = out + 34603008;                   // 6 x 2304
    float* h     = out + (size_t)BS_ * V_;           // tail: hset output

    const bool ws_ok = ws_size >= (size_t)(24576000ULL * 2 + HS * 2);
    __hip_bfloat16* Wf_t   = (__hip_bfloat16*)d_ws;              // [32000][768]
    __hip_bfloat16* hbf_ws = (__hip_bfloat16*)((char*)d_ws + 49152000);

    // ---- weight transpose/convert pre-pass ----
    const size_t DD = (size_t)D_ * D_, DF = (size_t)D_ * F_;
    const size_t QKVL = (size_t)NQKV_ * D_;
    transp_k<<<dim3(D_/32, D_/32, L_), 256, 0, stream>>>(Wq, DD, Wqkv_t,          QKVL, D_, D_);
    transp_k<<<dim3(D_/32, D_/32, L_), 256, 0, stream>>>(Wk, DD, Wqkv_t + DD,     QKVL, D_, D_);
    transp_k<<<dim3(D_/32, D_/32, L_), 256, 0, stream>>>(Wv, DD, Wqkv_t + 2 * DD, QKVL, D_, D_);
    transp_k<<<dim3(D_/32, D_/32, L_), 256, 0, stream>>>(Wo, DD, Wo_t,            DD,   D_, D_);
    transp_k<<<dim3(F_/32, D_/32, L_), 256, 0, stream>>>(W1, DF, W1_t,            DF,   F_, D_);
    transp_k<<<dim3(D_/32, F_/32, L_), 256, 0, stream>>>(W2, DF, W2_t,            DF,   D_, F_);
    bcat_k<<<L_, 256, 0, stream>>>(bq, bk, bv, bqkv);
    if (ws_ok)
        transp_k<<<dim3(V_/32, D_/32, 1), 256, 0, stream>>>(Wf, 0, Wf_t, 0, V_, D_);

    embed_k<<<BS_, 256, 0, stream>>>(x, tok, pos, h, h_bf);

    const dim3 gQKV(NQKV_/128, BS_/128);   // (18, 16)
    const dim3 gFF1(F_/128,    BS_/128);   // (24, 16)
    const dim3 gOUT(D_/128,    BS_/64);    // (6, 32)
    const dim3 gA(S_/64, B_*H_);           // (16, 24)
    for (int i = 0; i < L_; ++i) {
        mgemm_k<128,128,0,false,true,false,false,true><<<gQKV, 256, 0, stream>>>(
            h_bf, Wqkv_t + (size_t)i * QKVL, bqkv + (size_t)i * NQKV_, nullptr, qkv_bf, vT, BS_, NQKV_, D_);
        fattn_k<<<gA, 256, 0, stream>>>(qkv_bf, vT, att_bf);
        mgemm_k<64,128,0,true,false,false,false,false><<<gOUT, 256, 0, stream>>>(
            att_bf, Wo_t + (size_t)i * DD, bo + (size_t)i * D_, tmp, nullptr, nullptr, BS_, D_, D_);
        addln_k<<<BS_, 256, 0, stream>>>(tmp, h, ln1g + (size_t)i * D_, ln1b + (size_t)i * D_, h1, h1_bf);
        mgemm_k<128,128,1,false,true,false,false,false><<<gFF1, 256, 0, stream>>>(
            h1_bf, W1_t + (size_t)i * DF, b1 + (size_t)i * F_, nullptr, ff_bf, nullptr, BS_, F_, D_);
        mgemm_k<64,128,0,true,false,false,false,false><<<gOUT, 256, 0, stream>>>(
            ff_bf, W2_t + (size_t)i * DF, b2 + (size_t)i * D_, tmp, nullptr, nullptr, BS_, D_, F_);
        addln_k<<<BS_, 256, 0, stream>>>(tmp, h1, ln2g + (size_t)i * D_, ln2b + (size_t)i * D_, h, h_bf);
    }

    if (ws_ok) {
        cvt_k<<<(int)(HS / 1024), 256, 0, stream>>>(h, hbf_ws, (int)HS);
        mgemm_k<128,128,0,true,false,true,true,false><<<dim3(BS_/128, V_/128), 256, 0, stream>>>(
            hbf_ws, Wf_t, bff, out, nullptr, nullptr, BS_, V_, D_);
    } else {
        gemm_k<<<dim3(V_/64, BS_/64), 256, 0, stream>>>(h, Wf, bff, out, BS_, V_, D_);
    }
    lsm_k<<<BS_, 256, 0, stream>>>(out);
}